// Round 1
// baseline (939.748 us; speedup 1.0000x reference)
//
#include <hip/hip_runtime.h>
#include <math.h>

#define FEAT 128
#define EMBED 64
#define CLS 40

// ---------------- degree / norm ----------------

__global__ void k_deg(const int* __restrict__ col, int* __restrict__ deg, int E) {
    int e = blockIdx.x * blockDim.x + threadIdx.x;
    if (e < E) atomicAdd(&deg[col[e]], 1);
}

__global__ void k_dinv(const int* __restrict__ deg, float* __restrict__ dinv, int N) {
    int v = blockIdx.x * blockDim.x + threadIdx.x;
    if (v < N) dinv[v] = rsqrtf((float)(deg[v] + 1));   // +1 = self loop; always > 0
}

// ---------------- layer 1 GEMM: A[v][:] = (x[v] @ W1) * dinv[v] ----------------

__global__ void k_gemm1(const float* __restrict__ x, const float* __restrict__ W1,
                        const float* __restrict__ dinv, float* __restrict__ A, int N) {
    __shared__ float w[FEAT * EMBED];                   // 32 KB
    for (int i = threadIdx.x; i < FEAT * EMBED / 4; i += blockDim.x)
        ((float4*)w)[i] = ((const float4*)W1)[i];
    __syncthreads();

    int wave = threadIdx.x >> 6;
    int lane = threadIdx.x & 63;
    int row  = blockIdx.x * 4 + wave;
    if (row >= N) return;

    const float* xr = x + (size_t)row * FEAT;
    float acc = 0.f;
#pragma unroll
    for (int k = 0; k < FEAT; k += 4) {
        float4 xv = *(const float4*)(xr + k);           // wave-uniform broadcast load
        acc += xv.x * w[(k + 0) * EMBED + lane];
        acc += xv.y * w[(k + 1) * EMBED + lane];
        acc += xv.z * w[(k + 2) * EMBED + lane];
        acc += xv.w * w[(k + 3) * EMBED + lane];
    }
    A[(size_t)row * EMBED + lane] = acc * dinv[row];
}

// ---------------- edge scatter (layer 1): B[dst] += A[src] ----------------

__global__ void k_scatter1(const int* __restrict__ ei, const float* __restrict__ A,
                           float* __restrict__ B, int E) {
    int wave = threadIdx.x >> 6;
    int lane = threadIdx.x & 63;
    int e = blockIdx.x * 4 + wave;
    if (e >= E) return;
    int src = ei[e];
    int dst = ei[E + e];
    float v = A[(size_t)src * EMBED + lane];
    atomicAdd(&B[(size_t)dst * EMBED + lane], v);
}

// ---------------- finalize layer 1: A = relu(dinv*(B + A) + b1) (in place) ----------------

__global__ void k_fin1(float* __restrict__ A, const float* __restrict__ B,
                       const float* __restrict__ dinv, const float* __restrict__ b1, int N) {
    int idx = blockIdx.x * blockDim.x + threadIdx.x;
    if (idx >= N * EMBED) return;
    int v = idx >> 6;
    int k = idx & 63;
    float h = dinv[v] * (B[idx] + A[idx]) + b1[k];
    A[idx] = fmaxf(h, 0.f);
}

// ---------------- layer 2 GEMM: G[v][:] = (A[v] @ W2) * dinv[v] ----------------

__global__ void k_gemm2(const float* __restrict__ A, const float* __restrict__ W2,
                        const float* __restrict__ dinv, float* __restrict__ G, int N) {
    __shared__ float w[EMBED * CLS];                    // 10 KB
    for (int i = threadIdx.x; i < EMBED * CLS; i += blockDim.x) w[i] = W2[i];
    __syncthreads();

    int wave = threadIdx.x >> 6;
    int lane = threadIdx.x & 63;
    int row  = blockIdx.x * 4 + wave;
    if (row >= N || lane >= CLS) return;

    const float* hr = A + (size_t)row * EMBED;
    float acc = 0.f;
#pragma unroll
    for (int k = 0; k < EMBED; ++k)
        acc += hr[k] * w[k * CLS + lane];
    G[(size_t)row * CLS + lane] = acc * dinv[row];
}

// ---------------- edge scatter (layer 2): C[dst] += G[src] ----------------

__global__ void k_scatter2(const int* __restrict__ ei, const float* __restrict__ G,
                           float* __restrict__ C, int E) {
    int wave = threadIdx.x >> 6;
    int lane = threadIdx.x & 63;
    int e = blockIdx.x * 4 + wave;
    if (e >= E || lane >= CLS) return;
    int src = ei[e];
    int dst = ei[E + e];
    atomicAdd(&C[(size_t)dst * CLS + lane], G[(size_t)src * CLS + lane]);
}

// ---------------- finalize layer 2 + log_softmax ----------------

__global__ void k_fin2(const float* __restrict__ C, const float* __restrict__ G,
                       const float* __restrict__ dinv, const float* __restrict__ b2,
                       float* __restrict__ out, int N) {
    int wave = threadIdx.x >> 6;
    int lane = threadIdx.x & 63;
    int row  = blockIdx.x * 4 + wave;
    if (row >= N) return;

    float logit = -INFINITY;
    if (lane < CLS) {
        size_t idx = (size_t)row * CLS + lane;
        logit = dinv[row] * (C[idx] + G[idx]) + b2[lane];
    }
    float m = logit;
#pragma unroll
    for (int o = 32; o > 0; o >>= 1) m = fmaxf(m, __shfl_xor(m, o));
    float ex = (lane < CLS) ? __expf(logit - m) : 0.f;
    float s = ex;
#pragma unroll
    for (int o = 32; o > 0; o >>= 1) s += __shfl_xor(s, o);
    if (lane < CLS) out[(size_t)row * CLS + lane] = logit - m - __logf(s);
}

// ---------------- launch ----------------

extern "C" void kernel_launch(void* const* d_in, const int* in_sizes, int n_in,
                              void* d_out, int out_size, void* d_ws, size_t ws_size,
                              hipStream_t stream) {
    const float* x  = (const float*)d_in[0];
    const int*   ei = (const int*)d_in[1];
    const float* W1 = (const float*)d_in[2];
    const float* b1 = (const float*)d_in[3];
    const float* W2 = (const float*)d_in[4];
    const float* b2 = (const float*)d_in[5];
    float* out = (float*)d_out;

    const int N = in_sizes[0] / FEAT;       // 100000
    const int E = in_sizes[1] / 2;          // 1600000

    // workspace layout (bytes)
    char* ws = (char*)d_ws;
    int*   deg  = (int*)ws;                                    // N ints
    float* dinv = (float*)(ws + (size_t)N * 4);                // N floats
    float* A    = (float*)(ws + (size_t)N * 8);                // N*64 (h0*dinv, then h)
    float* B    = (float*)(ws + (size_t)N * 8 + (size_t)N * EMBED * 4);   // N*64 (agg1, then G)
    float* C    = (float*)(ws + (size_t)N * 8 + (size_t)N * EMBED * 8);   // N*40 (agg2)
    float* G    = B;   // reuse agg1 space for layer-2 pre-scaled features

    // zero accumulators (harness poisons ws with 0xAA; must re-init every call)
    hipMemsetAsync(deg, 0, (size_t)N * 4, stream);
    hipMemsetAsync(A + (size_t)N * EMBED, 0, (size_t)N * EMBED * 4, stream);  // B
    hipMemsetAsync(C, 0, (size_t)N * CLS * 4, stream);

    k_deg<<<(E + 255) / 256, 256, 0, stream>>>(ei + E, deg, E);
    k_dinv<<<(N + 255) / 256, 256, 0, stream>>>(deg, dinv, N);

    k_gemm1<<<(N + 3) / 4, 256, 0, stream>>>(x, W1, dinv, A, N);
    k_scatter1<<<(E + 3) / 4, 256, 0, stream>>>(ei, A, B, E);
    k_fin1<<<((size_t)N * EMBED + 255) / 256, 256, 0, stream>>>(A, B, dinv, b1, N);

    k_gemm2<<<(N + 3) / 4, 256, 0, stream>>>(A, W2, dinv, G, N);
    // NOTE: G aliases B — k_gemm2 reads A only, writes G; agg1 content is dead. Safe.
    k_scatter2<<<(E + 3) / 4, 256, 0, stream>>>(ei, G, C, E);
    k_fin2<<<(N + 3) / 4, 256, 0, stream>>>(C, G, dinv, b2, out, N);
}

// Round 2
// 671.349 us; speedup vs baseline: 1.3998x; 1.3998x over previous
//
#include <hip/hip_runtime.h>
#include <math.h>

#define FEAT 128
#define EMBED 64
#define CLS 40

#define SCAN_BS 256
#define SCAN_ITEMS 4
#define SCAN_ELEMS 1024   // SCAN_BS * SCAN_ITEMS

// ---------------- degree / norm ----------------

__global__ void k_deg(const int* __restrict__ col, int* __restrict__ deg, int E) {
    int e = blockIdx.x * blockDim.x + threadIdx.x;
    if (e < E) atomicAdd(&deg[col[e]], 1);
}

__global__ void k_dinv(const int* __restrict__ deg, float* __restrict__ dinv, int N) {
    int v = blockIdx.x * blockDim.x + threadIdx.x;
    if (v < N) dinv[v] = rsqrtf((float)(deg[v] + 1));   // +1 self loop; always > 0
}

// ---------------- exclusive scan of deg -> rowptr (3 kernels) ----------------

__global__ void k_scan_block(const int* __restrict__ deg, int* __restrict__ rowptr,
                             int* __restrict__ bsums, int N) {
    __shared__ int sh[SCAN_BS];
    int base = blockIdx.x * SCAN_ELEMS + threadIdx.x * SCAN_ITEMS;
    int v[SCAN_ITEMS];
    int tsum = 0;
#pragma unroll
    for (int i = 0; i < SCAN_ITEMS; ++i) {
        v[i] = (base + i < N) ? deg[base + i] : 0;
        tsum += v[i];
    }
    sh[threadIdx.x] = tsum;
    __syncthreads();
    for (int off = 1; off < SCAN_BS; off <<= 1) {            // Hillis-Steele inclusive
        int t = (threadIdx.x >= (unsigned)off) ? sh[threadIdx.x - off] : 0;
        __syncthreads();
        sh[threadIdx.x] += t;
        __syncthreads();
    }
    int excl = sh[threadIdx.x] - tsum;
    if (threadIdx.x == SCAN_BS - 1) bsums[blockIdx.x] = sh[SCAN_BS - 1];
    int run = excl;
#pragma unroll
    for (int i = 0; i < SCAN_ITEMS; ++i) {
        if (base + i < N) rowptr[base + i] = run;
        run += v[i];
    }
}

__global__ void k_scan_bsums(int* __restrict__ bsums, int nb) {   // single block, nb <= 256
    __shared__ int sh[256];
    int t = threadIdx.x;
    int val = (t < nb) ? bsums[t] : 0;
    sh[t] = val;
    __syncthreads();
    for (int off = 1; off < 256; off <<= 1) {
        int u = (t >= off) ? sh[t - off] : 0;
        __syncthreads();
        sh[t] += u;
        __syncthreads();
    }
    if (t < nb) bsums[t] = sh[t] - val;   // exclusive
}

__global__ void k_scan_add(int* __restrict__ rowptr, int* __restrict__ next,
                           const int* __restrict__ bsums, int N, int E) {
    int i = blockIdx.x * blockDim.x + threadIdx.x;
    if (i < N) {
        int r = rowptr[i] + bsums[i / SCAN_ELEMS];
        rowptr[i] = r;
        next[i] = r;
    }
    if (i == N) rowptr[N] = E;
}

// ---------------- CSR fill (by destination) ----------------

__global__ void k_fill(const int* __restrict__ ei, int* __restrict__ next,
                       int* __restrict__ csr, int E) {
    int e = blockIdx.x * blockDim.x + threadIdx.x;
    if (e >= E) return;
    int src = ei[e];
    int dst = ei[E + e];
    int pos = atomicAdd(&next[dst], 1);
    csr[pos] = src;
}

// ---------------- layer 1 GEMM: A[v][:] = (x[v] @ W1) * dinv[v] ----------------

__global__ void k_gemm1(const float* __restrict__ x, const float* __restrict__ W1,
                        const float* __restrict__ dinv, float* __restrict__ A, int N) {
    __shared__ float w[FEAT * EMBED];                   // 32 KB
    for (int i = threadIdx.x; i < FEAT * EMBED / 4; i += blockDim.x)
        ((float4*)w)[i] = ((const float4*)W1)[i];
    __syncthreads();

    int wave = threadIdx.x >> 6;
    int lane = threadIdx.x & 63;
    int row  = blockIdx.x * 4 + wave;
    if (row >= N) return;

    const float* xr = x + (size_t)row * FEAT;
    float acc = 0.f;
#pragma unroll
    for (int k = 0; k < FEAT; k += 4) {
        float4 xv = *(const float4*)(xr + k);
        acc += xv.x * w[(k + 0) * EMBED + lane];
        acc += xv.y * w[(k + 1) * EMBED + lane];
        acc += xv.z * w[(k + 2) * EMBED + lane];
        acc += xv.w * w[(k + 3) * EMBED + lane];
    }
    A[(size_t)row * EMBED + lane] = acc * dinv[row];
}

// ---------------- gather layer 1 + finalize: H = relu(dinv*(sum + self) + b1) ----------------

__global__ void k_gather_fin1(const int* __restrict__ rowptr, const int* __restrict__ csr,
                              const float* __restrict__ A, const float* __restrict__ dinv,
                              const float* __restrict__ b1, float* __restrict__ H, int N) {
    int wave = threadIdx.x >> 6;
    int lane = threadIdx.x & 63;
    int v = blockIdx.x * 4 + wave;
    if (v >= N) return;
    int beg = rowptr[v], end = rowptr[v + 1];
    float acc = 0.f;
    int j = beg;
    for (; j + 1 < end; j += 2) {                       // 2 independent gathers in flight
        int s0 = csr[j], s1 = csr[j + 1];
        float a0 = A[(size_t)s0 * EMBED + lane];
        float a1 = A[(size_t)s1 * EMBED + lane];
        acc += a0 + a1;
    }
    if (j < end) acc += A[(size_t)csr[j] * EMBED + lane];
    float h = dinv[v] * (acc + A[(size_t)v * EMBED + lane]) + b1[lane];
    H[(size_t)v * EMBED + lane] = fmaxf(h, 0.f);
}

// ---------------- layer 2 GEMM: G[v][:] = (H[v] @ W2) * dinv[v] ----------------

__global__ void k_gemm2(const float* __restrict__ H, const float* __restrict__ W2,
                        const float* __restrict__ dinv, float* __restrict__ G, int N) {
    __shared__ float w[EMBED * CLS];                    // 10 KB
    for (int i = threadIdx.x; i < EMBED * CLS; i += blockDim.x) w[i] = W2[i];
    __syncthreads();

    int wave = threadIdx.x >> 6;
    int lane = threadIdx.x & 63;
    int row  = blockIdx.x * 4 + wave;
    if (row >= N || lane >= CLS) return;

    const float* hr = H + (size_t)row * EMBED;
    float acc = 0.f;
#pragma unroll
    for (int k = 0; k < EMBED; ++k)
        acc += hr[k] * w[k * CLS + lane];
    G[(size_t)row * CLS + lane] = acc * dinv[row];
}

// ---------------- gather layer 2 + bias + log_softmax ----------------

__global__ void k_gather_fin2(const int* __restrict__ rowptr, const int* __restrict__ csr,
                              const float* __restrict__ G, const float* __restrict__ dinv,
                              const float* __restrict__ b2, float* __restrict__ out, int N) {
    int wave = threadIdx.x >> 6;
    int lane = threadIdx.x & 63;
    int v = blockIdx.x * 4 + wave;
    if (v >= N) return;
    int beg = rowptr[v], end = rowptr[v + 1];

    float acc = 0.f;
    for (int j = beg; j < end; ++j) {
        int s = csr[j];
        if (lane < CLS) acc += G[(size_t)s * CLS + lane];
    }

    float logit = -INFINITY;
    if (lane < CLS) {
        size_t idx = (size_t)v * CLS + lane;
        logit = dinv[v] * (acc + G[idx]) + b2[lane];
    }
    float m = logit;
#pragma unroll
    for (int o = 32; o > 0; o >>= 1) m = fmaxf(m, __shfl_xor(m, o));
    float ex = (lane < CLS) ? __expf(logit - m) : 0.f;
    float s = ex;
#pragma unroll
    for (int o = 32; o > 0; o >>= 1) s += __shfl_xor(s, o);
    if (lane < CLS) out[(size_t)v * CLS + lane] = logit - m - __logf(s);
}

// ---------------- launch ----------------

extern "C" void kernel_launch(void* const* d_in, const int* in_sizes, int n_in,
                              void* d_out, int out_size, void* d_ws, size_t ws_size,
                              hipStream_t stream) {
    const float* x  = (const float*)d_in[0];
    const int*   ei = (const int*)d_in[1];
    const float* W1 = (const float*)d_in[2];
    const float* b1 = (const float*)d_in[3];
    const float* W2 = (const float*)d_in[4];
    const float* b2 = (const float*)d_in[5];
    float* out = (float*)d_out;

    const int N = in_sizes[0] / FEAT;       // 100000
    const int E = in_sizes[1] / 2;          // 1600000
    const int NB = (N + SCAN_ELEMS - 1) / SCAN_ELEMS;   // 98

    // workspace layout
    char* ws = (char*)d_ws;
    size_t off = 0;
    int*   deg    = (int*)(ws + off);  off += (size_t)N * 4;
    float* dinv   = (float*)(ws + off); off += (size_t)N * 4;
    int*   rowptr = (int*)(ws + off);  off += (size_t)(N + 1) * 4;
    int*   next   = (int*)(ws + off);  off += (size_t)N * 4;
    int*   bsums  = (int*)(ws + off);  off += 1024;
    int*   csr    = (int*)(ws + off);  off += (size_t)E * 4;
    float* A      = (float*)(ws + off); off += (size_t)N * EMBED * 4;
    float* H      = (float*)(ws + off); off += (size_t)N * EMBED * 4;
    float* G      = A;   // A is dead once H is computed; reuse for layer-2 logits table

    // only deg needs zeroing; everything else is fully written before read
    hipMemsetAsync(deg, 0, (size_t)N * 4, stream);

    k_deg<<<(E + 255) / 256, 256, 0, stream>>>(ei + E, deg, E);
    k_dinv<<<(N + 255) / 256, 256, 0, stream>>>(deg, dinv, N);

    k_scan_block<<<NB, SCAN_BS, 0, stream>>>(deg, rowptr, bsums, N);
    k_scan_bsums<<<1, 256, 0, stream>>>(bsums, NB);
    k_scan_add<<<(N + 1 + 255) / 256, 256, 0, stream>>>(rowptr, next, bsums, N, E);

    k_fill<<<(E + 255) / 256, 256, 0, stream>>>(ei, next, csr, E);

    k_gemm1<<<(N + 3) / 4, 256, 0, stream>>>(x, W1, dinv, A, N);
    k_gather_fin1<<<(N + 3) / 4, 256, 0, stream>>>(rowptr, csr, A, dinv, b1, H, N);

    k_gemm2<<<(N + 3) / 4, 256, 0, stream>>>(H, W2, dinv, G, N);
    k_gather_fin2<<<(N + 3) / 4, 256, 0, stream>>>(rowptr, csr, G, dinv, b2, out, N);
}

// Round 3
// 383.768 us; speedup vs baseline: 2.4487x; 1.7494x over previous
//
#include <hip/hip_runtime.h>
#include <math.h>

#define FEAT 128
#define EMBED 64
#define CLS 40
#define CLSP 48          // padded to 3 MFMA col-tiles

#define SCAN_BS 256
#define SCAN_ITEMS 4
#define SCAN_ELEMS 1024  // SCAN_BS * SCAN_ITEMS

typedef __attribute__((ext_vector_type(8))) short s8v;    // 8 bf16 (4 VGPRs)
typedef __attribute__((ext_vector_type(4))) float f32x4;  // MFMA acc

static __device__ __forceinline__ float bf2f(unsigned short u) {
    union { unsigned int i; float f; } c; c.i = ((unsigned int)u) << 16; return c.f;
}
static __device__ __forceinline__ unsigned short f2bf(float f) {
    union { float f; unsigned int i; } c; c.f = f;
    unsigned int x = c.i;
    x += 0x7fffu + ((x >> 16) & 1u);   // RNE
    return (unsigned short)(x >> 16);
}

// ---------------- degree / norm ----------------

__global__ void k_deg(const int* __restrict__ col, int* __restrict__ deg, int E) {
    int e = blockIdx.x * blockDim.x + threadIdx.x;
    if (e < E) atomicAdd(&deg[col[e]], 1);
}

__global__ void k_dinv(const int* __restrict__ deg, float* __restrict__ dinv, int N) {
    int v = blockIdx.x * blockDim.x + threadIdx.x;
    if (v < N) dinv[v] = rsqrtf((float)(deg[v] + 1));
}

// ---------------- exclusive scan of deg -> rowptr ----------------

__global__ void k_scan_block(const int* __restrict__ deg, int* __restrict__ rowptr,
                             int* __restrict__ bsums, int N) {
    __shared__ int sh[SCAN_BS];
    int base = blockIdx.x * SCAN_ELEMS + threadIdx.x * SCAN_ITEMS;
    int v[SCAN_ITEMS];
    int tsum = 0;
#pragma unroll
    for (int i = 0; i < SCAN_ITEMS; ++i) {
        v[i] = (base + i < N) ? deg[base + i] : 0;
        tsum += v[i];
    }
    sh[threadIdx.x] = tsum;
    __syncthreads();
    for (int off = 1; off < SCAN_BS; off <<= 1) {
        int t = (threadIdx.x >= (unsigned)off) ? sh[threadIdx.x - off] : 0;
        __syncthreads();
        sh[threadIdx.x] += t;
        __syncthreads();
    }
    int excl = sh[threadIdx.x] - tsum;
    if (threadIdx.x == SCAN_BS - 1) bsums[blockIdx.x] = sh[SCAN_BS - 1];
    int run = excl;
#pragma unroll
    for (int i = 0; i < SCAN_ITEMS; ++i) {
        if (base + i < N) rowptr[base + i] = run;
        run += v[i];
    }
}

__global__ void k_scan_bsums(int* __restrict__ bsums, int nb) {   // nb <= 256
    __shared__ int sh[256];
    int t = threadIdx.x;
    int val = (t < nb) ? bsums[t] : 0;
    sh[t] = val;
    __syncthreads();
    for (int off = 1; off < 256; off <<= 1) {
        int u = (t >= off) ? sh[t - off] : 0;
        __syncthreads();
        sh[t] += u;
        __syncthreads();
    }
    if (t < nb) bsums[t] = sh[t] - val;
}

__global__ void k_scan_add(int* __restrict__ rowptr, int* __restrict__ next,
                           const int* __restrict__ bsums, int N, int E) {
    int i = blockIdx.x * blockDim.x + threadIdx.x;
    if (i < N) {
        int r = rowptr[i] + bsums[i / SCAN_ELEMS];
        rowptr[i] = r;
        next[i] = r;
    }
    if (i == N) rowptr[N] = E;
}

// ---------------- CSR fill (dst-major) ----------------

__global__ void k_fill(const int* __restrict__ ei, int* __restrict__ next,
                       int* __restrict__ csr, int E) {
    int e = blockIdx.x * blockDim.x + threadIdx.x;
    if (e >= E) return;
    int src = ei[e];
    int dst = ei[E + e];
    int pos = atomicAdd(&next[dst], 1);
    csr[pos] = src;
}

// ---------------- convert: xb = bf16(x * dinv[row]), 8 elems/thread ----------------

__global__ void k_convert(const float* __restrict__ x, const float* __restrict__ dinv,
                          unsigned short* __restrict__ xb, int total8) {
    int t = blockIdx.x * blockDim.x + threadIdx.x;
    if (t >= total8) return;
    size_t base = (size_t)t * 8;
    float dv = dinv[(int)(base >> 7)];        // FEAT=128 per row
    float4 a = *(const float4*)(x + base);
    float4 b = *(const float4*)(x + base + 4);
    s8v s;
    s[0] = (short)f2bf(a.x * dv); s[1] = (short)f2bf(a.y * dv);
    s[2] = (short)f2bf(a.z * dv); s[3] = (short)f2bf(a.w * dv);
    s[4] = (short)f2bf(b.x * dv); s[5] = (short)f2bf(b.y * dv);
    s[6] = (short)f2bf(b.z * dv); s[7] = (short)f2bf(b.w * dv);
    *(s8v*)(xb + base) = s;
}

// ---------------- GEMM1 (MFMA): A1[v][:] = bf16( xb[v] @ W1 ) ----------------
// xb already contains dinv[v]*x[v].

__global__ __launch_bounds__(256) void k_gemm1(const unsigned short* __restrict__ xb,
                                               const float* __restrict__ W1,
                                               unsigned short* __restrict__ A1, int N) {
    __shared__ unsigned short Wt[EMBED * 136];        // W^T, K padded 128->136 (17.4 KB)
    for (int i = threadIdx.x; i < FEAT * EMBED; i += 256) {
        int k = i >> 6, n = i & 63;
        Wt[n * 136 + k] = f2bf(W1[i]);
    }
    __syncthreads();

    int wv = threadIdx.x >> 6, lane = threadIdx.x & 63;
    int g = lane >> 4, r = lane & 15;
    int arow = blockIdx.x * 64 + wv * 16 + r;

    s8v z = {};
    s8v a[4];
#pragma unroll
    for (int ks = 0; ks < 4; ++ks)
        a[ks] = (arow < N) ? *(const s8v*)(xb + (size_t)arow * FEAT + ks * 32 + g * 8) : z;

    f32x4 acc[4];
#pragma unroll
    for (int nt = 0; nt < 4; ++nt) acc[nt] = (f32x4){0.f, 0.f, 0.f, 0.f};

#pragma unroll
    for (int nt = 0; nt < 4; ++nt) {
        int n0 = nt * 16;
#pragma unroll
        for (int ks = 0; ks < 4; ++ks) {
            s8v b = *(const s8v*)&Wt[(n0 + r) * 136 + ks * 32 + g * 8];
            acc[nt] = __builtin_amdgcn_mfma_f32_16x16x32_bf16(a[ks], b, acc[nt], 0, 0, 0);
        }
    }

    int orow0 = blockIdx.x * 64 + wv * 16 + g * 4;    // C: col=lane&15, row=4*(lane>>4)+q
#pragma unroll
    for (int nt = 0; nt < 4; ++nt)
#pragma unroll
        for (int q = 0; q < 4; ++q) {
            int orow = orow0 + q;
            if (orow < N) A1[(size_t)orow * EMBED + nt * 16 + r] = f2bf(acc[nt][q]);
        }
}

// ---------------- gather layer 1: Hb = bf16( dinv * relu(dinv*(sum+self)+b1) ) ----------------

__global__ void k_gf1(const int* __restrict__ rowptr, const int* __restrict__ csr,
                      const unsigned short* __restrict__ A1, const float* __restrict__ dinv,
                      const float* __restrict__ b1, unsigned short* __restrict__ Hb, int N) {
    int wv = threadIdx.x >> 6, lane = threadIdx.x & 63;
    int v = blockIdx.x * 4 + wv;
    if (v >= N) return;
    int beg = rowptr[v], end = rowptr[v + 1];

    float acc = 0.f;
    int j = beg;
    for (; j + 7 < end; j += 8) {
        int s0 = csr[j + 0], s1 = csr[j + 1], s2 = csr[j + 2], s3 = csr[j + 3];
        int s4 = csr[j + 4], s5 = csr[j + 5], s6 = csr[j + 6], s7 = csr[j + 7];
        float v0 = bf2f(A1[(size_t)s0 * EMBED + lane]);
        float v1 = bf2f(A1[(size_t)s1 * EMBED + lane]);
        float v2 = bf2f(A1[(size_t)s2 * EMBED + lane]);
        float v3 = bf2f(A1[(size_t)s3 * EMBED + lane]);
        float v4 = bf2f(A1[(size_t)s4 * EMBED + lane]);
        float v5 = bf2f(A1[(size_t)s5 * EMBED + lane]);
        float v6 = bf2f(A1[(size_t)s6 * EMBED + lane]);
        float v7 = bf2f(A1[(size_t)s7 * EMBED + lane]);
        acc += ((v0 + v1) + (v2 + v3)) + ((v4 + v5) + (v6 + v7));
    }
    for (; j < end; ++j) acc += bf2f(A1[(size_t)csr[j] * EMBED + lane]);

    float dv = dinv[v];
    float h = dv * (acc + bf2f(A1[(size_t)v * EMBED + lane])) + b1[lane];
    h = fmaxf(h, 0.f);
    Hb[(size_t)v * EMBED + lane] = f2bf(h * dv);      // pre-scale for layer 2
}

// ---------------- GEMM2 (MFMA): Gb[v][:] = bf16( Hb[v] @ W2 ) ----------------

__global__ __launch_bounds__(256) void k_gemm2(const unsigned short* __restrict__ Hb,
                                               const float* __restrict__ W2,
                                               unsigned short* __restrict__ Gb, int N) {
    __shared__ unsigned short Wt[CLSP * 72];          // W2^T, cols padded 40->48, K 64->72
    for (int i = threadIdx.x; i < CLSP * EMBED; i += 256) {
        int n = i >> 6, k = i & 63;
        Wt[n * 72 + k] = (n < CLS) ? f2bf(W2[k * CLS + n]) : 0;
    }
    __syncthreads();

    int wv = threadIdx.x >> 6, lane = threadIdx.x & 63;
    int g = lane >> 4, r = lane & 15;
    int arow = blockIdx.x * 64 + wv * 16 + r;

    s8v z = {};
    s8v a[2];
#pragma unroll
    for (int ks = 0; ks < 2; ++ks)
        a[ks] = (arow < N) ? *(const s8v*)(Hb + (size_t)arow * EMBED + ks * 32 + g * 8) : z;

    f32x4 acc[3];
#pragma unroll
    for (int nt = 0; nt < 3; ++nt) acc[nt] = (f32x4){0.f, 0.f, 0.f, 0.f};

#pragma unroll
    for (int nt = 0; nt < 3; ++nt)
#pragma unroll
        for (int ks = 0; ks < 2; ++ks) {
            s8v b = *(const s8v*)&Wt[(nt * 16 + r) * 72 + ks * 32 + g * 8];
            acc[nt] = __builtin_amdgcn_mfma_f32_16x16x32_bf16(a[ks], b, acc[nt], 0, 0, 0);
        }

    int orow0 = blockIdx.x * 64 + wv * 16 + g * 4;
#pragma unroll
    for (int nt = 0; nt < 3; ++nt) {
        int col = nt * 16 + r;
        if (col >= CLS) continue;
#pragma unroll
        for (int q = 0; q < 4; ++q) {
            int orow = orow0 + q;
            if (orow < N) Gb[(size_t)orow * CLS + col] = f2bf(acc[nt][q]);
        }
    }
}

// ---------------- gather layer 2 + bias + log_softmax ----------------

__global__ void k_gf2(const int* __restrict__ rowptr, const int* __restrict__ csr,
                      const unsigned short* __restrict__ Gb, const float* __restrict__ dinv,
                      const float* __restrict__ b2, float* __restrict__ out, int N) {
    int wv = threadIdx.x >> 6, lane = threadIdx.x & 63;
    int v = blockIdx.x * 4 + wv;
    if (v >= N) return;
    int beg = rowptr[v], end = rowptr[v + 1];
    bool act = lane < CLS;

    float acc = 0.f;
    int j = beg;
    for (; j + 7 < end; j += 8) {
        int s0 = csr[j + 0], s1 = csr[j + 1], s2 = csr[j + 2], s3 = csr[j + 3];
        int s4 = csr[j + 4], s5 = csr[j + 5], s6 = csr[j + 6], s7 = csr[j + 7];
        if (act) {
            float v0 = bf2f(Gb[(size_t)s0 * CLS + lane]);
            float v1 = bf2f(Gb[(size_t)s1 * CLS + lane]);
            float v2 = bf2f(Gb[(size_t)s2 * CLS + lane]);
            float v3 = bf2f(Gb[(size_t)s3 * CLS + lane]);
            float v4 = bf2f(Gb[(size_t)s4 * CLS + lane]);
            float v5 = bf2f(Gb[(size_t)s5 * CLS + lane]);
            float v6 = bf2f(Gb[(size_t)s6 * CLS + lane]);
            float v7 = bf2f(Gb[(size_t)s7 * CLS + lane]);
            acc += ((v0 + v1) + (v2 + v3)) + ((v4 + v5) + (v6 + v7));
        }
    }
    for (; j < end; ++j) {
        int s = csr[j];
        if (act) acc += bf2f(Gb[(size_t)s * CLS + lane]);
    }

    float logit = -INFINITY;
    if (act) logit = dinv[v] * (acc + bf2f(Gb[(size_t)v * CLS + lane])) + b2[lane];
    float m = logit;
#pragma unroll
    for (int o = 32; o > 0; o >>= 1) m = fmaxf(m, __shfl_xor(m, o));
    float ex = act ? __expf(logit - m) : 0.f;
    float s = ex;
#pragma unroll
    for (int o = 32; o > 0; o >>= 1) s += __shfl_xor(s, o);
    if (act) out[(size_t)v * CLS + lane] = logit - m - __logf(s);
}

// ---------------- launch ----------------

extern "C" void kernel_launch(void* const* d_in, const int* in_sizes, int n_in,
                              void* d_out, int out_size, void* d_ws, size_t ws_size,
                              hipStream_t stream) {
    const float* x  = (const float*)d_in[0];
    const int*   ei = (const int*)d_in[1];
    const float* W1 = (const float*)d_in[2];
    const float* b1 = (const float*)d_in[3];
    const float* W2 = (const float*)d_in[4];
    const float* b2 = (const float*)d_in[5];
    float* out = (float*)d_out;

    const int N = in_sizes[0] / FEAT;       // 100000
    const int E = in_sizes[1] / 2;          // 1600000
    const int NB = (N + SCAN_ELEMS - 1) / SCAN_ELEMS;

    char* ws = (char*)d_ws;
    size_t off = 0;
    auto alloc = [&](size_t bytes) { char* p = ws + off; off = (off + bytes + 255) & ~(size_t)255; return p; };
    int*   deg    = (int*)alloc((size_t)N * 4);
    float* dinv   = (float*)alloc((size_t)N * 4);
    int*   rowptr = (int*)alloc((size_t)(N + 1) * 4);
    int*   next   = (int*)alloc((size_t)N * 4);
    int*   bsums  = (int*)alloc(1024);
    int*   csr    = (int*)alloc((size_t)E * 4);
    unsigned short* xb = (unsigned short*)alloc((size_t)N * FEAT * 2);
    unsigned short* A1 = (unsigned short*)alloc((size_t)N * EMBED * 2);
    unsigned short* Hb = (unsigned short*)alloc((size_t)N * EMBED * 2);
    unsigned short* Gb = (unsigned short*)alloc((size_t)N * CLS * 2);

    hipMemsetAsync(deg, 0, (size_t)N * 4, stream);

    k_deg<<<(E + 255) / 256, 256, 0, stream>>>(ei + E, deg, E);
    k_dinv<<<(N + 255) / 256, 256, 0, stream>>>(deg, dinv, N);

    k_scan_block<<<NB, SCAN_BS, 0, stream>>>(deg, rowptr, bsums, N);
    k_scan_bsums<<<1, 256, 0, stream>>>(bsums, NB);
    k_scan_add<<<(N + 1 + 255) / 256, 256, 0, stream>>>(rowptr, next, bsums, N, E);
    k_fill<<<(E + 255) / 256, 256, 0, stream>>>(ei, next, csr, E);

    k_convert<<<((N * FEAT / 8) + 255) / 256, 256, 0, stream>>>(x, dinv, xb, N * FEAT / 8);

    k_gemm1<<<(N + 63) / 64, 256, 0, stream>>>(xb, W1, A1, N);
    k_gf1<<<(N + 3) / 4, 256, 0, stream>>>(rowptr, csr, A1, dinv, b1, Hb, N);

    k_gemm2<<<(N + 63) / 64, 256, 0, stream>>>(Hb, W2, Gb, N);
    k_gf2<<<(N + 3) / 4, 256, 0, stream>>>(rowptr, csr, Gb, dinv, b2, out, N);
}

// Round 4
// 216.368 us; speedup vs baseline: 4.3433x; 1.7737x over previous
//
#include <hip/hip_runtime.h>
#include <math.h>

#define FEAT 128
#define EMBED 64
#define CLS 40
#define GSTR 64          // padded Gb row stride (128B-aligned rows)

#define GRP 512          // nodes per bucket (pow2)
#define GSH 9            // log2(GRP)
#define STRIDE 12288     // pairs-buffer slots per bucket (mean fill ~8163)
#define T1 2048          // edges per phase-1 tile

typedef __attribute__((ext_vector_type(8))) short s8v;    // 8 bf16
typedef __attribute__((ext_vector_type(4))) float f32x4;  // MFMA acc

static __device__ __forceinline__ float bf2f(unsigned short u) {
    union { unsigned int i; float f; } c; c.i = ((unsigned int)u) << 16; return c.f;
}
static __device__ __forceinline__ unsigned short f2bf(float f) {
    union { float f; unsigned int i; } c; c.f = f;
    unsigned int x = c.i;
    x += 0x7fffu + ((x >> 16) & 1u);   // RNE
    return (unsigned short)(x >> 16);
}

// ---------------- cursor init: cursor[b] = b*STRIDE ----------------

__global__ void k_initcur(int* __restrict__ cursor, int B) {
    int t = blockIdx.x * blockDim.x + threadIdx.x;
    if (t < B) cursor[t] = t * STRIDE;
}

// ---------------- phase 1: LDS counting-sort tiles into bucketed pairs ----------------

__global__ __launch_bounds__(256) void k_p1(const int* __restrict__ ei,
                                            unsigned long long* __restrict__ pairs,
                                            int* __restrict__ cursor, int E, int B) {
    __shared__ unsigned long long pl[T1];            // 16 KB
    __shared__ int hist[256], base[256], gbase[256], lcnt[256], scanbuf[256];
    int tid = threadIdx.x;
    int tile0 = blockIdx.x * T1;
    int cnt = min(T1, E - tile0);

    hist[tid] = 0; lcnt[tid] = 0;
    __syncthreads();

    int s[T1 / 256], d[T1 / 256];
#pragma unroll
    for (int i = 0; i < T1 / 256; ++i) {
        int k = i * 256 + tid;
        if (k < cnt) {
            s[i] = ei[tile0 + k];
            d[i] = ei[E + tile0 + k];
            atomicAdd(&hist[d[i] >> GSH], 1);
        }
    }
    __syncthreads();

    int h = hist[tid];
    scanbuf[tid] = h;
    __syncthreads();
    for (int off = 1; off < 256; off <<= 1) {        // inclusive Hillis-Steele
        int t = (tid >= off) ? scanbuf[tid - off] : 0;
        __syncthreads();
        scanbuf[tid] += t;
        __syncthreads();
    }
    base[tid] = scanbuf[tid] - h;                    // exclusive
    gbase[tid] = (tid < B && h > 0) ? atomicAdd(&cursor[tid], h) : 0;
    __syncthreads();

#pragma unroll
    for (int i = 0; i < T1 / 256; ++i) {
        int k = i * 256 + tid;
        if (k < cnt) {
            int b = d[i] >> GSH;
            int pos = base[b] + atomicAdd(&lcnt[b], 1);
            pl[pos] = ((unsigned long long)(unsigned)d[i] << 32) | (unsigned)s[i];
        }
    }
    __syncthreads();

    for (int k = tid; k < cnt; k += 256) {           // linear copy-out: runs coalesce
        unsigned long long p = pl[k];
        int b = (int)(p >> (32 + GSH));
        pairs[(size_t)gbase[b] + (k - base[b])] = p;
    }
}

// ---------------- bucket-count scan -> csrBase; rowptr[N] = E ----------------

__global__ void k_bscan(const int* __restrict__ cursor, int* __restrict__ csrBase,
                        int* __restrict__ rowptr, int B, int E, int N) {
    __shared__ int sh[256];
    int t = threadIdx.x;
    int c = (t < B) ? cursor[t] - t * STRIDE : 0;
    sh[t] = c;
    __syncthreads();
    for (int off = 1; off < 256; off <<= 1) {
        int u = (t >= off) ? sh[t - off] : 0;
        __syncthreads();
        sh[t] += u;
        __syncthreads();
    }
    if (t < B) csrBase[t] = sh[t] - c;
    if (t == 0) rowptr[N] = E;
}

// ---------------- phase 2: per-bucket CSR scatter + deg/dinv/rowptr ----------------

__global__ __launch_bounds__(512) void k_p2(const unsigned long long* __restrict__ pairs,
                                            const int* __restrict__ cursor,
                                            const int* __restrict__ csrBase,
                                            int* __restrict__ csr, int* __restrict__ rowptr,
                                            float* __restrict__ dinv, int N) {
    __shared__ int hist[GRP], cur[GRP], scanbuf[GRP];
    int t = threadIdx.x;
    int b = blockIdx.x;
    int v0 = b << GSH;
    size_t reg0 = (size_t)b * STRIDE;
    int cnt = cursor[b] - b * STRIDE;

    hist[t] = 0;
    __syncthreads();
    for (int k = t; k < cnt; k += GRP)
        atomicAdd(&hist[(int)(pairs[reg0 + k] >> 32) - v0], 1);
    __syncthreads();

    int h = hist[t];
    scanbuf[t] = h;
    __syncthreads();
    for (int off = 1; off < GRP; off <<= 1) {
        int u = (t >= off) ? scanbuf[t - off] : 0;
        __syncthreads();
        scanbuf[t] += u;
        __syncthreads();
    }
    int excl = scanbuf[t] - h;
    int cB = csrBase[b];
    int v = v0 + t;
    if (v < N) {
        rowptr[v] = cB + excl;
        dinv[v] = rsqrtf((float)(h + 1));            // +1 = self loop
    }
    cur[t] = excl;
    __syncthreads();

    for (int k = t; k < cnt; k += GRP) {
        unsigned long long p = pairs[reg0 + k];
        int l = (int)(p >> 32) - v0;
        int pos = atomicAdd(&cur[l], 1);
        csr[cB + pos] = (int)(p & 0xffffffffu);      // writes within ~32KB window
    }
}

// ---------------- GEMM1 (MFMA, fused fp32->bf16 + dinv scale on A) ----------------
// A1[v][:] = bf16( (dinv[v]*x[v]) @ W1 )

__global__ __launch_bounds__(256) void k_gemm1(const float* __restrict__ x,
                                               const float* __restrict__ W1,
                                               const float* __restrict__ dinv,
                                               unsigned short* __restrict__ A1, int N) {
    __shared__ unsigned short Wt[EMBED * 136];       // W^T, K padded 128->136
    for (int i = threadIdx.x; i < FEAT * EMBED; i += 256) {
        int k = i >> 6, n = i & 63;
        Wt[n * 136 + k] = f2bf(W1[i]);
    }
    __syncthreads();

    int wv = threadIdx.x >> 6, lane = threadIdx.x & 63;
    int g = lane >> 4, r = lane & 15;
    int arow = blockIdx.x * 64 + wv * 16 + r;
    bool rowok = arow < N;
    float dv = rowok ? dinv[arow] : 0.f;

    s8v a[4];
#pragma unroll
    for (int ks = 0; ks < 4; ++ks) {
        if (rowok) {
            const float* p = x + (size_t)arow * FEAT + ks * 32 + g * 8;
            float4 p0 = *(const float4*)p;
            float4 p1 = *(const float4*)(p + 4);
            s8v t;
            t[0] = (short)f2bf(p0.x * dv); t[1] = (short)f2bf(p0.y * dv);
            t[2] = (short)f2bf(p0.z * dv); t[3] = (short)f2bf(p0.w * dv);
            t[4] = (short)f2bf(p1.x * dv); t[5] = (short)f2bf(p1.y * dv);
            t[6] = (short)f2bf(p1.z * dv); t[7] = (short)f2bf(p1.w * dv);
            a[ks] = t;
        } else {
            s8v z = {};
            a[ks] = z;
        }
    }

    f32x4 acc[4];
#pragma unroll
    for (int nt = 0; nt < 4; ++nt) acc[nt] = (f32x4){0.f, 0.f, 0.f, 0.f};

#pragma unroll
    for (int nt = 0; nt < 4; ++nt) {
        int n0 = nt * 16;
#pragma unroll
        for (int ks = 0; ks < 4; ++ks) {
            s8v bfr = *(const s8v*)&Wt[(n0 + r) * 136 + ks * 32 + g * 8];
            acc[nt] = __builtin_amdgcn_mfma_f32_16x16x32_bf16(a[ks], bfr, acc[nt], 0, 0, 0);
        }
    }

    int orow0 = blockIdx.x * 64 + wv * 16 + g * 4;   // C: col=lane&15, row=4*(lane>>4)+q
#pragma unroll
    for (int nt = 0; nt < 4; ++nt)
#pragma unroll
        for (int q = 0; q < 4; ++q) {
            int orow = orow0 + q;
            if (orow < N) A1[(size_t)orow * EMBED + nt * 16 + r] = f2bf(acc[nt][q]);
        }
}

// ---------------- gather layer 1: Hb = bf16( dinv * relu(dinv*(sum+self)+b1) ) ----------------

__global__ void k_gf1(const int* __restrict__ rowptr, const int* __restrict__ csr,
                      const unsigned short* __restrict__ A1, const float* __restrict__ dinv,
                      const float* __restrict__ b1, unsigned short* __restrict__ Hb, int N) {
    int wv = threadIdx.x >> 6, lane = threadIdx.x & 63;
    int v = blockIdx.x * 4 + wv;
    if (v >= N) return;
    int beg = rowptr[v], end = rowptr[v + 1];

    float acc = 0.f;
    int j = beg;
    for (; j + 7 < end; j += 8) {
        int s0 = csr[j + 0], s1 = csr[j + 1], s2 = csr[j + 2], s3 = csr[j + 3];
        int s4 = csr[j + 4], s5 = csr[j + 5], s6 = csr[j + 6], s7 = csr[j + 7];
        float v0 = bf2f(A1[(size_t)s0 * EMBED + lane]);
        float v1 = bf2f(A1[(size_t)s1 * EMBED + lane]);
        float v2 = bf2f(A1[(size_t)s2 * EMBED + lane]);
        float v3 = bf2f(A1[(size_t)s3 * EMBED + lane]);
        float v4 = bf2f(A1[(size_t)s4 * EMBED + lane]);
        float v5 = bf2f(A1[(size_t)s5 * EMBED + lane]);
        float v6 = bf2f(A1[(size_t)s6 * EMBED + lane]);
        float v7 = bf2f(A1[(size_t)s7 * EMBED + lane]);
        acc += ((v0 + v1) + (v2 + v3)) + ((v4 + v5) + (v6 + v7));
    }
    for (; j < end; ++j) acc += bf2f(A1[(size_t)csr[j] * EMBED + lane]);

    float dv = dinv[v];
    float h = dv * (acc + bf2f(A1[(size_t)v * EMBED + lane])) + b1[lane];
    h = fmaxf(h, 0.f);
    Hb[(size_t)v * EMBED + lane] = f2bf(h * dv);     // pre-scale for layer 2
}

// ---------------- GEMM2 (MFMA): Gb[v][:] = bf16( Hb[v] @ W2 ), stride GSTR ----------------

__global__ __launch_bounds__(256) void k_gemm2(const unsigned short* __restrict__ Hb,
                                               const float* __restrict__ W2,
                                               unsigned short* __restrict__ Gb, int N) {
    __shared__ unsigned short Wt[48 * 72];           // W2^T, cols padded 40->48, K 64->72
    for (int i = threadIdx.x; i < 48 * EMBED; i += 256) {
        int n = i >> 6, k = i & 63;
        Wt[n * 72 + k] = (n < CLS) ? f2bf(W2[k * CLS + n]) : 0;
    }
    __syncthreads();

    int wv = threadIdx.x >> 6, lane = threadIdx.x & 63;
    int g = lane >> 4, r = lane & 15;
    int arow = blockIdx.x * 64 + wv * 16 + r;

    s8v z = {};
    s8v a[2];
#pragma unroll
    for (int ks = 0; ks < 2; ++ks)
        a[ks] = (arow < N) ? *(const s8v*)(Hb + (size_t)arow * EMBED + ks * 32 + g * 8) : z;

    f32x4 acc[3];
#pragma unroll
    for (int nt = 0; nt < 3; ++nt) acc[nt] = (f32x4){0.f, 0.f, 0.f, 0.f};

#pragma unroll
    for (int nt = 0; nt < 3; ++nt)
#pragma unroll
        for (int ks = 0; ks < 2; ++ks) {
            s8v bfr = *(const s8v*)&Wt[(nt * 16 + r) * 72 + ks * 32 + g * 8];
            acc[nt] = __builtin_amdgcn_mfma_f32_16x16x32_bf16(a[ks], bfr, acc[nt], 0, 0, 0);
        }

    int orow0 = blockIdx.x * 64 + wv * 16 + g * 4;
#pragma unroll
    for (int nt = 0; nt < 3; ++nt) {
        int col = nt * 16 + r;
        if (col >= CLS) continue;
#pragma unroll
        for (int q = 0; q < 4; ++q) {
            int orow = orow0 + q;
            if (orow < N) Gb[(size_t)orow * GSTR + col] = f2bf(acc[nt][q]);
        }
    }
}

// ---------------- gather layer 2 + bias + log_softmax ----------------

__global__ void k_gf2(const int* __restrict__ rowptr, const int* __restrict__ csr,
                      const unsigned short* __restrict__ Gb, const float* __restrict__ dinv,
                      const float* __restrict__ b2, float* __restrict__ out, int N) {
    int wv = threadIdx.x >> 6, lane = threadIdx.x & 63;
    int v = blockIdx.x * 4 + wv;
    if (v >= N) return;
    int beg = rowptr[v], end = rowptr[v + 1];
    bool act = lane < CLS;

    float acc = 0.f;
    int j = beg;
    for (; j + 7 < end; j += 8) {
        int s0 = csr[j + 0], s1 = csr[j + 1], s2 = csr[j + 2], s3 = csr[j + 3];
        int s4 = csr[j + 4], s5 = csr[j + 5], s6 = csr[j + 6], s7 = csr[j + 7];
        if (act) {
            float v0 = bf2f(Gb[(size_t)s0 * GSTR + lane]);
            float v1 = bf2f(Gb[(size_t)s1 * GSTR + lane]);
            float v2 = bf2f(Gb[(size_t)s2 * GSTR + lane]);
            float v3 = bf2f(Gb[(size_t)s3 * GSTR + lane]);
            float v4 = bf2f(Gb[(size_t)s4 * GSTR + lane]);
            float v5 = bf2f(Gb[(size_t)s5 * GSTR + lane]);
            float v6 = bf2f(Gb[(size_t)s6 * GSTR + lane]);
            float v7 = bf2f(Gb[(size_t)s7 * GSTR + lane]);
            acc += ((v0 + v1) + (v2 + v3)) + ((v4 + v5) + (v6 + v7));
        }
    }
    for (; j < end; ++j) {
        int s = csr[j];
        if (act) acc += bf2f(Gb[(size_t)s * GSTR + lane]);
    }

    float logit = -INFINITY;
    if (act) logit = dinv[v] * (acc + bf2f(Gb[(size_t)v * GSTR + lane])) + b2[lane];
    float m = logit;
#pragma unroll
    for (int o = 32; o > 0; o >>= 1) m = fmaxf(m, __shfl_xor(m, o));
    float ex = act ? __expf(logit - m) : 0.f;
    float s = ex;
#pragma unroll
    for (int o = 32; o > 0; o >>= 1) s += __shfl_xor(s, o);
    if (act) out[(size_t)v * CLS + lane] = logit - m - __logf(s);
}

// ---------------- launch ----------------

extern "C" void kernel_launch(void* const* d_in, const int* in_sizes, int n_in,
                              void* d_out, int out_size, void* d_ws, size_t ws_size,
                              hipStream_t stream) {
    const float* x  = (const float*)d_in[0];
    const int*   ei = (const int*)d_in[1];
    const float* W1 = (const float*)d_in[2];
    const float* b1 = (const float*)d_in[3];
    const float* W2 = (const float*)d_in[4];
    const float* b2 = (const float*)d_in[5];
    float* out = (float*)d_out;

    const int N = in_sizes[0] / FEAT;           // 100000
    const int E = in_sizes[1] / 2;              // 1600000
    const int B = (N + GRP - 1) >> GSH;         // 196 buckets (<=256)

    char* ws = (char*)d_ws;
    size_t off = 0;
    auto alloc = [&](size_t bytes) { char* p = ws + off; off = (off + bytes + 255) & ~(size_t)255; return p; };
    int*   cursor  = (int*)alloc(256 * 4);
    int*   csrBase = (int*)alloc(256 * 4);
    float* dinv    = (float*)alloc((size_t)N * 4);
    int*   rowptr  = (int*)alloc((size_t)(N + 1) * 4);
    int*   csr     = (int*)alloc((size_t)E * 4);
    // union region: pairs (19.3 MB) dead before A1/Hb are written
    char*  region  = alloc(((size_t)B * STRIDE * 8 > (size_t)N * EMBED * 4)
                               ? (size_t)B * STRIDE * 8 : (size_t)N * EMBED * 4);
    unsigned long long* pairs = (unsigned long long*)region;
    unsigned short* A1 = (unsigned short*)region;
    unsigned short* Hb = (unsigned short*)(region + (size_t)N * EMBED * 2);
    unsigned short* Gb = (unsigned short*)alloc((size_t)N * GSTR * 2);

    k_initcur<<<1, 256, 0, stream>>>(cursor, B);
    k_p1<<<(E + T1 - 1) / T1, 256, 0, stream>>>(ei, pairs, cursor, E, B);
    k_bscan<<<1, 256, 0, stream>>>(cursor, csrBase, rowptr, B, E, N);
    k_p2<<<B, GRP, 0, stream>>>(pairs, cursor, csrBase, csr, rowptr, dinv, N);

    k_gemm1<<<(N + 63) / 64, 256, 0, stream>>>(x, W1, dinv, A1, N);
    k_gf1<<<(N + 3) / 4, 256, 0, stream>>>(rowptr, csr, A1, dinv, b1, Hb, N);

    k_gemm2<<<(N + 63) / 64, 256, 0, stream>>>(Hb, W2, Gb, N);
    k_gf2<<<(N + 3) / 4, 256, 0, stream>>>(rowptr, csr, Gb, dinv, b2, out, N);
}

// Round 5
// 175.749 us; speedup vs baseline: 5.3471x; 1.2311x over previous
//
#include <hip/hip_runtime.h>
#include <math.h>

#define FEAT 128
#define EMBED 64
#define CLS 40

#define GRP 512          // nodes per bucket (pow2)
#define GSH 9            // log2(GRP)
#define STRIDE 12288     // pairs-buffer slots per bucket (mean fill ~8163)
#define T1 2048          // edges per phase-1 tile

typedef __attribute__((ext_vector_type(8))) short s8v;    // 8 bf16
typedef __attribute__((ext_vector_type(4))) float f32x4;  // MFMA acc

static __device__ __forceinline__ float bf2f(unsigned short u) {
    union { unsigned int i; float f; } c; c.i = ((unsigned int)u) << 16; return c.f;
}
static __device__ __forceinline__ unsigned short f2bf(float f) {
    union { float f; unsigned int i; } c; c.f = f;
    unsigned int x = c.i;
    x += 0x7fffu + ((x >> 16) & 1u);   // RNE
    return (unsigned short)(x >> 16);
}

// ---------------- cursor init ----------------

__global__ void k_initcur(int* __restrict__ cursor, int B) {
    int t = blockIdx.x * blockDim.x + threadIdx.x;
    if (t < B) cursor[t] = t * STRIDE;
}

// ---------------- phase 1: LDS counting-sort tiles into bucketed pairs ----------------

__global__ __launch_bounds__(256) void k_p1(const int* __restrict__ ei,
                                            unsigned long long* __restrict__ pairs,
                                            int* __restrict__ cursor, int E, int B) {
    __shared__ unsigned long long pl[T1];            // 16 KB
    __shared__ int hist[256], base[256], gbase[256], lcnt[256], scanbuf[256];
    int tid = threadIdx.x;
    int tile0 = blockIdx.x * T1;
    int cnt = min(T1, E - tile0);

    hist[tid] = 0; lcnt[tid] = 0;
    __syncthreads();

    int s[T1 / 256], d[T1 / 256];
#pragma unroll
    for (int i = 0; i < T1 / 256; ++i) {
        int k = i * 256 + tid;
        if (k < cnt) {
            s[i] = ei[tile0 + k];
            d[i] = ei[E + tile0 + k];
            atomicAdd(&hist[d[i] >> GSH], 1);
        }
    }
    __syncthreads();

    int h = hist[tid];
    scanbuf[tid] = h;
    __syncthreads();
    for (int off = 1; off < 256; off <<= 1) {
        int t = (tid >= (unsigned)off) ? scanbuf[tid - off] : 0;
        __syncthreads();
        scanbuf[tid] += t;
        __syncthreads();
    }
    base[tid] = scanbuf[tid] - h;
    gbase[tid] = (tid < B && h > 0) ? atomicAdd(&cursor[tid], h) : 0;
    __syncthreads();

#pragma unroll
    for (int i = 0; i < T1 / 256; ++i) {
        int k = i * 256 + tid;
        if (k < cnt) {
            int b = d[i] >> GSH;
            int pos = base[b] + atomicAdd(&lcnt[b], 1);
            pl[pos] = ((unsigned long long)(unsigned)d[i] << 32) | (unsigned)s[i];
        }
    }
    __syncthreads();

    for (int k = tid; k < cnt; k += 256) {
        unsigned long long p = pl[k];
        int b = (int)(p >> (32 + GSH));
        pairs[(size_t)gbase[b] + (k - base[b])] = p;
    }
}

// ---------------- bucket-count scan -> csrBase; rowptr[N] = E ----------------

__global__ void k_bscan(const int* __restrict__ cursor, int* __restrict__ csrBase,
                        int* __restrict__ rowptr, int B, int E, int N) {
    __shared__ int sh[256];
    int t = threadIdx.x;
    int c = (t < B) ? cursor[t] - t * STRIDE : 0;
    sh[t] = c;
    __syncthreads();
    for (int off = 1; off < 256; off <<= 1) {
        int u = (t >= off) ? sh[t - off] : 0;
        __syncthreads();
        sh[t] += u;
        __syncthreads();
    }
    if (t < B) csrBase[t] = sh[t] - c;
    if (t == 0) rowptr[N] = E;
}

// ---------------- phase 2: per-bucket CSR scatter + deg/dinv/rowptr ----------------

__global__ __launch_bounds__(512) void k_p2(const unsigned long long* __restrict__ pairs,
                                            const int* __restrict__ cursor,
                                            const int* __restrict__ csrBase,
                                            int* __restrict__ csr, int* __restrict__ rowptr,
                                            float* __restrict__ dinv, int N) {
    __shared__ int hist[GRP], cur[GRP], scanbuf[GRP];
    int t = threadIdx.x;
    int b = blockIdx.x;
    int v0 = b << GSH;
    size_t reg0 = (size_t)b * STRIDE;
    int cnt = cursor[b] - b * STRIDE;

    hist[t] = 0;
    __syncthreads();
    for (int k = t; k < cnt; k += GRP)
        atomicAdd(&hist[(int)(pairs[reg0 + k] >> 32) - v0], 1);
    __syncthreads();

    int h = hist[t];
    scanbuf[t] = h;
    __syncthreads();
    for (int off = 1; off < GRP; off <<= 1) {
        int u = (t >= off) ? scanbuf[t - off] : 0;
        __syncthreads();
        scanbuf[t] += u;
        __syncthreads();
    }
    int excl = scanbuf[t] - h;
    int cB = csrBase[b];
    int v = v0 + t;
    if (v < N) {
        rowptr[v] = cB + excl;
        dinv[v] = rsqrtf((float)(h + 1));
    }
    cur[t] = excl;
    __syncthreads();

    for (int k = t; k < cnt; k += GRP) {
        unsigned long long p = pairs[reg0 + k];
        int l = (int)(p >> 32) - v0;
        int pos = atomicAdd(&cur[l], 1);
        csr[cB + pos] = (int)(p & 0xffffffffu);
    }
}

// ---------------- GEMM1 (MFMA, fused fp32->bf16 + dinv scale on A) ----------------

__global__ __launch_bounds__(256) void k_gemm1(const float* __restrict__ x,
                                               const float* __restrict__ W1,
                                               const float* __restrict__ dinv,
                                               unsigned short* __restrict__ A1, int N) {
    __shared__ unsigned short Wt[EMBED * 136];       // W^T, K padded 128->136
    for (int i = threadIdx.x; i < FEAT * EMBED; i += 256) {
        int k = i >> 6, n = i & 63;
        Wt[n * 136 + k] = f2bf(W1[i]);
    }
    __syncthreads();

    int wv = threadIdx.x >> 6, lane = threadIdx.x & 63;
    int g = lane >> 4, r = lane & 15;
    int arow = blockIdx.x * 64 + wv * 16 + r;
    bool rowok = arow < N;
    float dv = rowok ? dinv[arow] : 0.f;

    s8v a[4];
#pragma unroll
    for (int ks = 0; ks < 4; ++ks) {
        if (rowok) {
            const float* p = x + (size_t)arow * FEAT + ks * 32 + g * 8;
            float4 p0 = *(const float4*)p;
            float4 p1 = *(const float4*)(p + 4);
            s8v t;
            t[0] = (short)f2bf(p0.x * dv); t[1] = (short)f2bf(p0.y * dv);
            t[2] = (short)f2bf(p0.z * dv); t[3] = (short)f2bf(p0.w * dv);
            t[4] = (short)f2bf(p1.x * dv); t[5] = (short)f2bf(p1.y * dv);
            t[6] = (short)f2bf(p1.z * dv); t[7] = (short)f2bf(p1.w * dv);
            a[ks] = t;
        } else {
            s8v z = {};
            a[ks] = z;
        }
    }

    f32x4 acc[4];
#pragma unroll
    for (int nt = 0; nt < 4; ++nt) acc[nt] = (f32x4){0.f, 0.f, 0.f, 0.f};

#pragma unroll
    for (int nt = 0; nt < 4; ++nt) {
        int n0 = nt * 16;
#pragma unroll
        for (int ks = 0; ks < 4; ++ks) {
            s8v bfr = *(const s8v*)&Wt[(n0 + r) * 136 + ks * 32 + g * 8];
            acc[nt] = __builtin_amdgcn_mfma_f32_16x16x32_bf16(a[ks], bfr, acc[nt], 0, 0, 0);
        }
    }

    int orow0 = blockIdx.x * 64 + wv * 16 + g * 4;
#pragma unroll
    for (int nt = 0; nt < 4; ++nt)
#pragma unroll
        for (int q = 0; q < 4; ++q) {
            int orow = orow0 + q;
            if (orow < N) A1[(size_t)orow * EMBED + nt * 16 + r] = f2bf(acc[nt][q]);
        }
}

// ---------------- wide gather core: rowslot=lane>>4 (4 rows/load), dims=4*(lane&15) ----------------

struct F4 { float x, y, z, w; };

static __device__ __forceinline__ F4 ld4(const unsigned short* p) {
    ushort4 u = *(const ushort4*)p;                  // 8B/lane
    F4 f;
    f.x = bf2f(u.x); f.y = bf2f(u.y); f.z = bf2f(u.z); f.w = bf2f(u.w);
    return f;
}

// gather layer 1: Hb = bf16( dinv * relu(dinv*(sum+self)+b1) )
__global__ __launch_bounds__(256) void k_gf1(const int* __restrict__ rowptr,
                                             const int* __restrict__ csr,
                                             const unsigned short* __restrict__ A1,
                                             const float* __restrict__ dinv,
                                             const float* __restrict__ b1,
                                             unsigned short* __restrict__ Hb, int N) {
    int wv = threadIdx.x >> 6, lane = threadIdx.x & 63;
    int v = blockIdx.x * 4 + wv;
    if (v >= N) return;
    int rs = lane >> 4;          // row slot 0..3
    int dp = (lane & 15) * 4;    // dims [dp..dp+3]
    int beg = rowptr[v], end = rowptr[v + 1];

    float ax = 0.f, ay = 0.f, az = 0.f, aw = 0.f;
    int j = beg;
    for (; j + 15 < end; j += 16) {
        int s0 = csr[j + rs], s1 = csr[j + 4 + rs], s2 = csr[j + 8 + rs], s3 = csr[j + 12 + rs];
        F4 f0 = ld4(A1 + (size_t)s0 * EMBED + dp);
        F4 f1 = ld4(A1 + (size_t)s1 * EMBED + dp);
        F4 f2 = ld4(A1 + (size_t)s2 * EMBED + dp);
        F4 f3 = ld4(A1 + (size_t)s3 * EMBED + dp);
        ax += (f0.x + f1.x) + (f2.x + f3.x);
        ay += (f0.y + f1.y) + (f2.y + f3.y);
        az += (f0.z + f1.z) + (f2.z + f3.z);
        aw += (f0.w + f1.w) + (f2.w + f3.w);
    }
    for (; j + 3 < end; j += 4) {
        int s0 = csr[j + rs];
        F4 f0 = ld4(A1 + (size_t)s0 * EMBED + dp);
        ax += f0.x; ay += f0.y; az += f0.z; aw += f0.w;
    }
    if (j + rs < end) {
        int s0 = csr[j + rs];
        F4 f0 = ld4(A1 + (size_t)s0 * EMBED + dp);
        ax += f0.x; ay += f0.y; az += f0.z; aw += f0.w;
    }
    // fold the 4 row slots (xor 16, 32)
#pragma unroll
    for (int o = 16; o < 64; o <<= 1) {
        ax += __shfl_xor(ax, o); ay += __shfl_xor(ay, o);
        az += __shfl_xor(az, o); aw += __shfl_xor(aw, o);
    }

    float dv = dinv[v];
    F4 sf = ld4(A1 + (size_t)v * EMBED + dp);
    float4 bv = *(const float4*)(b1 + dp);
    float hx = fmaxf(dv * (ax + sf.x) + bv.x, 0.f);
    float hy = fmaxf(dv * (ay + sf.y) + bv.y, 0.f);
    float hz = fmaxf(dv * (az + sf.z) + bv.z, 0.f);
    float hw = fmaxf(dv * (aw + sf.w) + bv.w, 0.f);
    if (rs == 0) {
        ushort4 o;
        o.x = f2bf(hx * dv); o.y = f2bf(hy * dv);
        o.z = f2bf(hz * dv); o.w = f2bf(hw * dv);
        *(ushort4*)(Hb + (size_t)v * EMBED + dp) = o;
    }
}

// gather layer 2 (linearity): Pb = bf16( dinv[v] * (sum Hb[src] + Hb[v]) )
__global__ __launch_bounds__(256) void k_gf2h(const int* __restrict__ rowptr,
                                              const int* __restrict__ csr,
                                              const unsigned short* __restrict__ Hb,
                                              const float* __restrict__ dinv,
                                              unsigned short* __restrict__ Pb, int N) {
    int wv = threadIdx.x >> 6, lane = threadIdx.x & 63;
    int v = blockIdx.x * 4 + wv;
    if (v >= N) return;
    int rs = lane >> 4;
    int dp = (lane & 15) * 4;
    int beg = rowptr[v], end = rowptr[v + 1];

    float ax = 0.f, ay = 0.f, az = 0.f, aw = 0.f;
    int j = beg;
    for (; j + 15 < end; j += 16) {
        int s0 = csr[j + rs], s1 = csr[j + 4 + rs], s2 = csr[j + 8 + rs], s3 = csr[j + 12 + rs];
        F4 f0 = ld4(Hb + (size_t)s0 * EMBED + dp);
        F4 f1 = ld4(Hb + (size_t)s1 * EMBED + dp);
        F4 f2 = ld4(Hb + (size_t)s2 * EMBED + dp);
        F4 f3 = ld4(Hb + (size_t)s3 * EMBED + dp);
        ax += (f0.x + f1.x) + (f2.x + f3.x);
        ay += (f0.y + f1.y) + (f2.y + f3.y);
        az += (f0.z + f1.z) + (f2.z + f3.z);
        aw += (f0.w + f1.w) + (f2.w + f3.w);
    }
    for (; j + 3 < end; j += 4) {
        int s0 = csr[j + rs];
        F4 f0 = ld4(Hb + (size_t)s0 * EMBED + dp);
        ax += f0.x; ay += f0.y; az += f0.z; aw += f0.w;
    }
    if (j + rs < end) {
        int s0 = csr[j + rs];
        F4 f0 = ld4(Hb + (size_t)s0 * EMBED + dp);
        ax += f0.x; ay += f0.y; az += f0.z; aw += f0.w;
    }
#pragma unroll
    for (int o = 16; o < 64; o <<= 1) {
        ax += __shfl_xor(ax, o); ay += __shfl_xor(ay, o);
        az += __shfl_xor(az, o); aw += __shfl_xor(aw, o);
    }

    float dv = dinv[v];
    F4 sf = ld4(Hb + (size_t)v * EMBED + dp);
    if (rs == 0) {
        ushort4 o;
        o.x = f2bf(dv * (ax + sf.x)); o.y = f2bf(dv * (ay + sf.y));
        o.z = f2bf(dv * (az + sf.z)); o.w = f2bf(dv * (aw + sf.w));
        *(ushort4*)(Pb + (size_t)v * EMBED + dp) = o;
    }
}

// ---------------- final: out = log_softmax(Pb @ W2 + b2) (MFMA + fused softmax) ----------------

__global__ __launch_bounds__(256) void k_fin(const unsigned short* __restrict__ Pb,
                                             const float* __restrict__ W2,
                                             const float* __restrict__ b2,
                                             float* __restrict__ out, int N) {
    __shared__ unsigned short Wt[48 * 72];           // W2^T, cols padded 40->48, K 64->72
    for (int i = threadIdx.x; i < 48 * EMBED; i += 256) {
        int n = i >> 6, k = i & 63;
        Wt[n * 72 + k] = (n < CLS) ? f2bf(W2[k * CLS + n]) : 0;
    }
    __syncthreads();

    int wv = threadIdx.x >> 6, lane = threadIdx.x & 63;
    int g = lane >> 4, r = lane & 15;
    int arow = blockIdx.x * 64 + wv * 16 + r;

    s8v z = {};
    s8v a[2];
#pragma unroll
    for (int ks = 0; ks < 2; ++ks)
        a[ks] = (arow < N) ? *(const s8v*)(Pb + (size_t)arow * EMBED + ks * 32 + g * 8) : z;

    f32x4 acc[3];
#pragma unroll
    for (int nt = 0; nt < 3; ++nt) acc[nt] = (f32x4){0.f, 0.f, 0.f, 0.f};

#pragma unroll
    for (int nt = 0; nt < 3; ++nt)
#pragma unroll
        for (int ks = 0; ks < 2; ++ks) {
            s8v bfr = *(const s8v*)&Wt[(nt * 16 + r) * 72 + ks * 32 + g * 8];
            acc[nt] = __builtin_amdgcn_mfma_f32_16x16x32_bf16(a[ks], bfr, acc[nt], 0, 0, 0);
        }

    // C layout: row = base + g*4 + q, col = nt*16 + r. Softmax reduces over r within 16-lane group.
    int orow0 = blockIdx.x * 64 + wv * 16 + g * 4;
    bool v2 = r < (CLS - 32);                        // nt==2 valid cols
#pragma unroll
    for (int q = 0; q < 4; ++q) {
        float l0 = acc[0][q] + b2[r];
        float l1 = acc[1][q] + b2[16 + r];
        float l2 = v2 ? acc[2][q] + b2[32 + r] : -INFINITY;
        float m = fmaxf(fmaxf(l0, l1), l2);
#pragma unroll
        for (int o = 1; o < 16; o <<= 1) m = fmaxf(m, __shfl_xor(m, o));
        float se = __expf(l0 - m) + __expf(l1 - m) + (v2 ? __expf(l2 - m) : 0.f);
#pragma unroll
        for (int o = 1; o < 16; o <<= 1) se += __shfl_xor(se, o);
        float lse = m + __logf(se);
        int orow = orow0 + q;
        if (orow < N) {
            float* op = out + (size_t)orow * CLS;
            op[r] = l0 - lse;
            op[16 + r] = l1 - lse;
            if (v2) op[32 + r] = l2 - lse;
        }
    }
}

// ---------------- launch ----------------

extern "C" void kernel_launch(void* const* d_in, const int* in_sizes, int n_in,
                              void* d_out, int out_size, void* d_ws, size_t ws_size,
                              hipStream_t stream) {
    const float* x  = (const float*)d_in[0];
    const int*   ei = (const int*)d_in[1];
    const float* W1 = (const float*)d_in[2];
    const float* b1 = (const float*)d_in[3];
    const float* W2 = (const float*)d_in[4];
    const float* b2 = (const float*)d_in[5];
    float* out = (float*)d_out;

    const int N = in_sizes[0] / FEAT;           // 100000
    const int E = in_sizes[1] / 2;              // 1600000
    const int B = (N + GRP - 1) >> GSH;         // 196 buckets (<=256)

    char* ws = (char*)d_ws;
    size_t off = 0;
    auto alloc = [&](size_t bytes) { char* p = ws + off; off = (off + bytes + 255) & ~(size_t)255; return p; };
    int*   cursor  = (int*)alloc(256 * 4);
    int*   csrBase = (int*)alloc(256 * 4);
    float* dinv    = (float*)alloc((size_t)N * 4);
    int*   rowptr  = (int*)alloc((size_t)(N + 1) * 4);
    int*   csr     = (int*)alloc((size_t)E * 4);
    // union region: pairs (19.3 MB) dead before A1/Hb written; Pb aliases A1 (dead after gf1)
    size_t regA = (size_t)B * STRIDE * 8;
    size_t regB = (size_t)N * EMBED * 4;        // A1 + Hb
    char*  region = alloc(regA > regB ? regA : regB);
    unsigned long long* pairs = (unsigned long long*)region;
    unsigned short* A1 = (unsigned short*)region;
    unsigned short* Hb = (unsigned short*)(region + (size_t)N * EMBED * 2);
    unsigned short* Pb = A1;                    // gf2h reads Hb, writes Pb (disjoint halves)

    k_initcur<<<1, 256, 0, stream>>>(cursor, B);
    k_p1<<<(E + T1 - 1) / T1, 256, 0, stream>>>(ei, pairs, cursor, E, B);
    k_bscan<<<1, 256, 0, stream>>>(cursor, csrBase, rowptr, B, E, N);
    k_p2<<<B, GRP, 0, stream>>>(pairs, cursor, csrBase, csr, rowptr, dinv, N);

    k_gemm1<<<(N + 63) / 64, 256, 0, stream>>>(x, W1, dinv, A1, N);
    k_gf1<<<(N + 3) / 4, 256, 0, stream>>>(rowptr, csr, A1, dinv, b1, Hb, N);
    k_gf2h<<<(N + 3) / 4, 256, 0, stream>>>(rowptr, csr, Hb, dinv, Pb, N);
    k_fin<<<(N + 63) / 64, 256, 0, stream>>>(Pb, W2, b2, out, N);
}

// Round 7
// 164.053 us; speedup vs baseline: 5.7283x; 1.0713x over previous
//
#include <hip/hip_runtime.h>
#include <math.h>

#define FEAT 128
#define EMBED 64
#define CLS 40

#define GRP 512          // nodes per bucket (pow2)
#define GSH 9            // log2(GRP)
#define STRIDE 12288     // pairs-buffer slots per bucket (mean fill ~8163)
#define T1 2048          // edges per phase-1 tile

typedef __attribute__((ext_vector_type(8))) short s8v;    // 8 bf16
typedef __attribute__((ext_vector_type(4))) float f32x4;  // MFMA acc

static __device__ __forceinline__ float bf2f(unsigned short u) {
    union { unsigned int i; float f; } c; c.i = ((unsigned int)u) << 16; return c.f;
}
static __device__ __forceinline__ unsigned short f2bf(float f) {
    union { float f; unsigned int i; } c; c.f = f;
    unsigned int x = c.i;
    x += 0x7fffu + ((x >> 16) & 1u);   // RNE
    return (unsigned short)(x >> 16);
}

// ---------------- cursor init ----------------

__global__ void k_initcur(int* __restrict__ cursor, int B) {
    int t = blockIdx.x * blockDim.x + threadIdx.x;
    if (t < B) cursor[t] = t * STRIDE;
}

// ---------------- phase 1: LDS counting-sort tiles into bucketed pairs ----------------

__global__ __launch_bounds__(256) void k_p1(const int* __restrict__ ei,
                                            unsigned long long* __restrict__ pairs,
                                            int* __restrict__ cursor, int E, int B) {
    __shared__ unsigned long long pl[T1];            // 16 KB
    __shared__ int hist[256], base[256], gbase[256], lcnt[256], scanbuf[256];
    int tid = threadIdx.x;
    int tile0 = blockIdx.x * T1;
    int cnt = min(T1, E - tile0);

    hist[tid] = 0; lcnt[tid] = 0;
    __syncthreads();

    int s[T1 / 256], d[T1 / 256];
#pragma unroll
    for (int i = 0; i < T1 / 256; ++i) {
        int k = i * 256 + tid;
        if (k < cnt) {
            s[i] = ei[tile0 + k];
            d[i] = ei[E + tile0 + k];
            atomicAdd(&hist[d[i] >> GSH], 1);
        }
    }
    __syncthreads();

    int h = hist[tid];
    scanbuf[tid] = h;
    __syncthreads();
    for (int off = 1; off < 256; off <<= 1) {
        int t = (tid >= (unsigned)off) ? scanbuf[tid - off] : 0;
        __syncthreads();
        scanbuf[tid] += t;
        __syncthreads();
    }
    base[tid] = scanbuf[tid] - h;
    gbase[tid] = (tid < B && h > 0) ? atomicAdd(&cursor[tid], h) : 0;
    __syncthreads();

#pragma unroll
    for (int i = 0; i < T1 / 256; ++i) {
        int k = i * 256 + tid;
        if (k < cnt) {
            int b = d[i] >> GSH;
            int pos = base[b] + atomicAdd(&lcnt[b], 1);
            pl[pos] = ((unsigned long long)(unsigned)d[i] << 32) | (unsigned)s[i];
        }
    }
    __syncthreads();

    for (int k = tid; k < cnt; k += 256) {
        unsigned long long p = pl[k];
        int b = (int)(p >> (32 + GSH));
        pairs[(size_t)gbase[b] + (k - base[b])] = p;
    }
}

// ---------------- bucket-count scan -> csrBase; rowptr[N] = E ----------------

__global__ void k_bscan(const int* __restrict__ cursor, int* __restrict__ csrBase,
                        int* __restrict__ rowptr, int B, int E, int N) {
    __shared__ int sh[256];
    int t = threadIdx.x;
    int c = (t < B) ? cursor[t] - t * STRIDE : 0;
    sh[t] = c;
    __syncthreads();
    for (int off = 1; off < 256; off <<= 1) {
        int u = (t >= off) ? sh[t - off] : 0;
        __syncthreads();
        sh[t] += u;
        __syncthreads();
    }
    if (t < B) csrBase[t] = sh[t] - c;
    if (t == 0) rowptr[N] = E;
}

// ---------------- phase 2: per-bucket CSR scatter + deg/dinv/rowptr ----------------

__global__ __launch_bounds__(512) void k_p2(const unsigned long long* __restrict__ pairs,
                                            const int* __restrict__ cursor,
                                            const int* __restrict__ csrBase,
                                            int* __restrict__ csr, int* __restrict__ rowptr,
                                            float* __restrict__ dinv, int N) {
    __shared__ int hist[GRP], cur[GRP], scanbuf[GRP];
    int t = threadIdx.x;
    int b = blockIdx.x;
    int v0 = b << GSH;
    size_t reg0 = (size_t)b * STRIDE;
    int cnt = cursor[b] - b * STRIDE;

    hist[t] = 0;
    __syncthreads();
    for (int k = t; k < cnt; k += GRP)
        atomicAdd(&hist[(int)(pairs[reg0 + k] >> 32) - v0], 1);
    __syncthreads();

    int h = hist[t];
    scanbuf[t] = h;
    __syncthreads();
    for (int off = 1; off < GRP; off <<= 1) {
        int u = (t >= off) ? scanbuf[t - off] : 0;
        __syncthreads();
        scanbuf[t] += u;
        __syncthreads();
    }
    int excl = scanbuf[t] - h;
    int cB = csrBase[b];
    int v = v0 + t;
    if (v < N) {
        rowptr[v] = cB + excl;
        dinv[v] = rsqrtf((float)(h + 1));
    }
    cur[t] = excl;
    __syncthreads();

    for (int k = t; k < cnt; k += GRP) {
        unsigned long long p = pairs[reg0 + k];
        int l = (int)(p >> 32) - v0;
        int pos = atomicAdd(&cur[l], 1);
        csr[cB + pos] = (int)(p & 0xffffffffu);
    }
}

// ---------------- GEMM1 (MFMA, fused fp32->bf16 + dinv scale on A) ----------------

__global__ __launch_bounds__(256) void k_gemm1(const float* __restrict__ x,
                                               const float* __restrict__ W1,
                                               const float* __restrict__ dinv,
                                               unsigned short* __restrict__ A1, int N) {
    __shared__ unsigned short Wt[EMBED * 136];       // W^T, K padded 128->136
    for (int i = threadIdx.x; i < FEAT * EMBED; i += 256) {
        int k = i >> 6, n = i & 63;
        Wt[n * 136 + k] = f2bf(W1[i]);
    }
    __syncthreads();

    int wv = threadIdx.x >> 6, lane = threadIdx.x & 63;
    int g = lane >> 4, r = lane & 15;
    int arow = blockIdx.x * 64 + wv * 16 + r;
    bool rowok = arow < N;
    float dv = rowok ? dinv[arow] : 0.f;

    s8v a[4];
#pragma unroll
    for (int ks = 0; ks < 4; ++ks) {
        if (rowok) {
            const float* p = x + (size_t)arow * FEAT + ks * 32 + g * 8;
            float4 p0 = *(const float4*)p;
            float4 p1 = *(const float4*)(p + 4);
            s8v t;
            t[0] = (short)f2bf(p0.x * dv); t[1] = (short)f2bf(p0.y * dv);
            t[2] = (short)f2bf(p0.z * dv); t[3] = (short)f2bf(p0.w * dv);
            t[4] = (short)f2bf(p1.x * dv); t[5] = (short)f2bf(p1.y * dv);
            t[6] = (short)f2bf(p1.z * dv); t[7] = (short)f2bf(p1.w * dv);
            a[ks] = t;
        } else {
            s8v z = {};
            a[ks] = z;
        }
    }

    f32x4 acc[4];
#pragma unroll
    for (int nt = 0; nt < 4; ++nt) acc[nt] = (f32x4){0.f, 0.f, 0.f, 0.f};

#pragma unroll
    for (int nt = 0; nt < 4; ++nt) {
        int n0 = nt * 16;
#pragma unroll
        for (int ks = 0; ks < 4; ++ks) {
            s8v bfr = *(const s8v*)&Wt[(n0 + r) * 136 + ks * 32 + g * 8];
            acc[nt] = __builtin_amdgcn_mfma_f32_16x16x32_bf16(a[ks], bfr, acc[nt], 0, 0, 0);
        }
    }

    int orow0 = blockIdx.x * 64 + wv * 16 + g * 4;
#pragma unroll
    for (int nt = 0; nt < 4; ++nt)
#pragma unroll
        for (int q = 0; q < 4; ++q) {
            int orow = orow0 + q;
            if (orow < N) A1[(size_t)orow * EMBED + nt * 16 + r] = f2bf(acc[nt][q]);
        }
}

// ---------------- wide gather: direct strided index loads (convergent, no shfl) ----------------
// rs = lane>>3 (slot 0..7), dp = (lane&7)*8 (8 dims = 16B per lane).
// Virtual index list: positions 0..cnt-2 = csr[beg..], position cnt-1 = self (v).
// Slot rs handles positions rs, rs+8, rs+16, ... ; 4 groups batched per iteration
// so 4 idx loads + 4 row loads are independently in flight.

#define ACC8(u)                                                              \
    a0 += bf2f((unsigned short)(u)[0]); a1 += bf2f((unsigned short)(u)[1]);  \
    a2 += bf2f((unsigned short)(u)[2]); a3 += bf2f((unsigned short)(u)[3]);  \
    a4 += bf2f((unsigned short)(u)[4]); a5 += bf2f((unsigned short)(u)[5]);  \
    a6 += bf2f((unsigned short)(u)[6]); a7 += bf2f((unsigned short)(u)[7]);

#define GATHER_ACC(TBL)                                                      \
    float a0=0,a1=0,a2=0,a3=0,a4=0,a5=0,a6=0,a7=0;                           \
    for (int p = rs; p < cnt; p += 32) {                                     \
        int pA = p, pB = p + 8, pC = p + 16, pD = p + 24;                    \
        int sA = (pA < cnt - 1) ? csr[beg + pA] : v;                         \
        int sB = (pB < cnt - 1) ? csr[beg + pB] : v;                         \
        int sC = (pC < cnt - 1) ? csr[beg + pC] : v;                         \
        int sD = (pD < cnt - 1) ? csr[beg + pD] : v;                         \
        { s8v u = *(const s8v*)(TBL + (size_t)sA * EMBED + dp); ACC8(u) }    \
        if (pB < cnt) { s8v u = *(const s8v*)(TBL + (size_t)sB * EMBED + dp); ACC8(u) } \
        if (pC < cnt) { s8v u = *(const s8v*)(TBL + (size_t)sC * EMBED + dp); ACC8(u) } \
        if (pD < cnt) { s8v u = *(const s8v*)(TBL + (size_t)sD * EMBED + dp); ACC8(u) } \
    }                                                                        \
    _Pragma("unroll")                                                        \
    for (int o = 8; o < 64; o <<= 1) {                                       \
        a0 += __shfl_xor(a0, o); a1 += __shfl_xor(a1, o);                    \
        a2 += __shfl_xor(a2, o); a3 += __shfl_xor(a3, o);                    \
        a4 += __shfl_xor(a4, o); a5 += __shfl_xor(a5, o);                    \
        a6 += __shfl_xor(a6, o); a7 += __shfl_xor(a7, o);                    \
    }

// gather layer 1: Hb = bf16( dinv * relu(dinv*sum + b1) )   (sum includes self)
__global__ __launch_bounds__(256) void k_gf1(const int* __restrict__ rowptr,
                                             const int* __restrict__ csr,
                                             const unsigned short* __restrict__ A1,
                                             const float* __restrict__ dinv,
                                             const float* __restrict__ b1,
                                             unsigned short* __restrict__ Hb, int N) {
    int wv = threadIdx.x >> 6, lane = threadIdx.x & 63;
    int v = blockIdx.x * 4 + wv;
    if (v >= N) return;
    int beg = rowptr[v];
    int cnt = rowptr[v + 1] - beg + 1;       // + self
    int rs = lane >> 3, dp = (lane & 7) * 8;

    GATHER_ACC(A1)

    if (rs == 0) {
        float dv = dinv[v];
        float4 bA = *(const float4*)(b1 + dp);
        float4 bB = *(const float4*)(b1 + dp + 4);
        float h0 = fmaxf(dv * a0 + bA.x, 0.f), h1 = fmaxf(dv * a1 + bA.y, 0.f);
        float h2 = fmaxf(dv * a2 + bA.z, 0.f), h3 = fmaxf(dv * a3 + bA.w, 0.f);
        float h4 = fmaxf(dv * a4 + bB.x, 0.f), h5 = fmaxf(dv * a5 + bB.y, 0.f);
        float h6 = fmaxf(dv * a6 + bB.z, 0.f), h7 = fmaxf(dv * a7 + bB.w, 0.f);
        s8v o;
        o[0] = (short)f2bf(h0 * dv); o[1] = (short)f2bf(h1 * dv);
        o[2] = (short)f2bf(h2 * dv); o[3] = (short)f2bf(h3 * dv);
        o[4] = (short)f2bf(h4 * dv); o[5] = (short)f2bf(h5 * dv);
        o[6] = (short)f2bf(h6 * dv); o[7] = (short)f2bf(h7 * dv);
        *(s8v*)(Hb + (size_t)v * EMBED + dp) = o;
    }
}

// gather layer 2 (linearity): Pb = bf16( dinv[v] * sum Hb )   (sum includes self)
__global__ __launch_bounds__(256) void k_gf2h(const int* __restrict__ rowptr,
                                              const int* __restrict__ csr,
                                              const unsigned short* __restrict__ Hb,
                                              const float* __restrict__ dinv,
                                              unsigned short* __restrict__ Pb, int N) {
    int wv = threadIdx.x >> 6, lane = threadIdx.x & 63;
    int v = blockIdx.x * 4 + wv;
    if (v >= N) return;
    int beg = rowptr[v];
    int cnt = rowptr[v + 1] - beg + 1;
    int rs = lane >> 3, dp = (lane & 7) * 8;

    GATHER_ACC(Hb)

    if (rs == 0) {
        float dv = dinv[v];
        s8v o;
        o[0] = (short)f2bf(dv * a0); o[1] = (short)f2bf(dv * a1);
        o[2] = (short)f2bf(dv * a2); o[3] = (short)f2bf(dv * a3);
        o[4] = (short)f2bf(dv * a4); o[5] = (short)f2bf(dv * a5);
        o[6] = (short)f2bf(dv * a6); o[7] = (short)f2bf(dv * a7);
        *(s8v*)(Pb + (size_t)v * EMBED + dp) = o;
    }
}

// ---------------- final: out = log_softmax(Pb @ W2 + b2) (MFMA + fused softmax) ----------------

__global__ __launch_bounds__(256) void k_fin(const unsigned short* __restrict__ Pb,
                                             const float* __restrict__ W2,
                                             const float* __restrict__ b2,
                                             float* __restrict__ out, int N) {
    __shared__ unsigned short Wt[48 * 72];           // W2^T, cols padded 40->48, K 64->72
    for (int i = threadIdx.x; i < 48 * EMBED; i += 256) {
        int n = i >> 6, k = i & 63;
        Wt[n * 72 + k] = (n < CLS) ? f2bf(W2[k * CLS + n]) : 0;
    }
    __syncthreads();

    int wv = threadIdx.x >> 6, lane = threadIdx.x & 63;
    int g = lane >> 4, r = lane & 15;
    int arow = blockIdx.x * 64 + wv * 16 + r;

    s8v z = {};
    s8v a[2];
#pragma unroll
    for (int ks = 0; ks < 2; ++ks)
        a[ks] = (arow < N) ? *(const s8v*)(Pb + (size_t)arow * EMBED + ks * 32 + g * 8) : z;

    f32x4 acc[3];
#pragma unroll
    for (int nt = 0; nt < 3; ++nt) acc[nt] = (f32x4){0.f, 0.f, 0.f, 0.f};

#pragma unroll
    for (int nt = 0; nt < 3; ++nt)
#pragma unroll
        for (int ks = 0; ks < 2; ++ks) {
            s8v bfr = *(const s8v*)&Wt[(nt * 16 + r) * 72 + ks * 32 + g * 8];
            acc[nt] = __builtin_amdgcn_mfma_f32_16x16x32_bf16(a[ks], bfr, acc[nt], 0, 0, 0);
        }

    int orow0 = blockIdx.x * 64 + wv * 16 + g * 4;
    bool v2 = r < (CLS - 32);
#pragma unroll
    for (int q = 0; q < 4; ++q) {
        float l0 = acc[0][q] + b2[r];
        float l1 = acc[1][q] + b2[16 + r];
        float l2 = v2 ? acc[2][q] + b2[32 + r] : -INFINITY;
        float m = fmaxf(fmaxf(l0, l1), l2);
#pragma unroll
        for (int o = 1; o < 16; o <<= 1) m = fmaxf(m, __shfl_xor(m, o));
        float se = __expf(l0 - m) + __expf(l1 - m) + (v2 ? __expf(l2 - m) : 0.f);
#pragma unroll
        for (int o = 1; o < 16; o <<= 1) se += __shfl_xor(se, o);
        float lse = m + __logf(se);
        int orow = orow0 + q;
        if (orow < N) {
            float* op = out + (size_t)orow * CLS;
            op[r] = l0 - lse;
            op[16 + r] = l1 - lse;
            if (v2) op[32 + r] = l2 - lse;
        }
    }
}

// ---------------- launch ----------------

extern "C" void kernel_launch(void* const* d_in, const int* in_sizes, int n_in,
                              void* d_out, int out_size, void* d_ws, size_t ws_size,
                              hipStream_t stream) {
    const float* x  = (const float*)d_in[0];
    const int*   ei = (const int*)d_in[1];
    const float* W1 = (const float*)d_in[2];
    const float* b1 = (const float*)d_in[3];
    const float* W2 = (const float*)d_in[4];
    const float* b2 = (const float*)d_in[5];
    float* out = (float*)d_out;

    const int N = in_sizes[0] / FEAT;           // 100000
    const int E = in_sizes[1] / 2;              // 1600000
    const int B = (N + GRP - 1) >> GSH;         // 196 buckets (<=256)

    char* ws = (char*)d_ws;
    size_t off = 0;
    auto alloc = [&](size_t bytes) { char* p = ws + off; off = (off + bytes + 255) & ~(size_t)255; return p; };
    int*   cursor  = (int*)alloc(256 * 4);
    int*   csrBase = (int*)alloc(256 * 4);
    float* dinv    = (float*)alloc((size_t)N * 4);
    int*   rowptr  = (int*)alloc((size_t)(N + 1) * 4);
    int*   csr     = (int*)alloc((size_t)E * 4);
    // union region: pairs (19.3 MB) dead before A1/Hb written; Pb aliases A1 (dead after gf1)
    size_t regA = (size_t)B * STRIDE * 8;
    size_t regB = (size_t)N * EMBED * 4;        // A1 + Hb
    char*  region = alloc(regA > regB ? regA : regB);
    unsigned long long* pairs = (unsigned long long*)region;
    unsigned short* A1 = (unsigned short*)region;
    unsigned short* Hb = (unsigned short*)(region + (size_t)N * EMBED * 2);
    unsigned short* Pb = A1;                    // gf2h reads Hb, writes Pb (disjoint halves)

    k_initcur<<<1, 256, 0, stream>>>(cursor, B);
    k_p1<<<(E + T1 - 1) / T1, 256, 0, stream>>>(ei, pairs, cursor, E, B);
    k_bscan<<<1, 256, 0, stream>>>(cursor, csrBase, rowptr, B, E, N);
    k_p2<<<B, GRP, 0, stream>>>(pairs, cursor, csrBase, csr, rowptr, dinv, N);

    k_gemm1<<<(N + 63) / 64, 256, 0, stream>>>(x, W1, dinv, A1, N);
    k_gf1<<<(N + 3) / 4, 256, 0, stream>>>(rowptr, csr, A1, dinv, b1, Hb, N);
    k_gf2h<<<(N + 3) / 4, 256, 0, stream>>>(rowptr, csr, Hb, dinv, Pb, N);
    k_fin<<<(N + 63) / 64, 256, 0, stream>>>(Pb, W2, b2, out, N);
}

// Round 8
// 142.335 us; speedup vs baseline: 6.6024x; 1.1526x over previous
//
#include <hip/hip_runtime.h>
#include <math.h>

#define FEAT 128
#define EMBED 64
#define CLS 40

#define GRP 512          // nodes per bucket (pow2)
#define GSH 9            // log2(GRP)
#define STRIDE 12288     // pairs-buffer slots per bucket (mean fill ~8163)
#define T1 2048          // edges per phase-1 tile

typedef __attribute__((ext_vector_type(8))) short s8v;    // 8 bf16
typedef __attribute__((ext_vector_type(4))) float f32x4;  // MFMA acc

static __device__ __forceinline__ float bf2f(unsigned short u) {
    union { unsigned int i; float f; } c; c.i = ((unsigned int)u) << 16; return c.f;
}
static __device__ __forceinline__ unsigned short f2bf(float f) {
    union { float f; unsigned int i; } c; c.f = f;
    unsigned int x = c.i;
    x += 0x7fffu + ((x >> 16) & 1u);   // RNE
    return (unsigned short)(x >> 16);
}

// ---------------- cursor init ----------------

__global__ void k_initcur(int* __restrict__ cursor, int B) {
    int t = blockIdx.x * blockDim.x + threadIdx.x;
    if (t < B) cursor[t] = t * STRIDE;
}

// ---------------- phase 1: LDS counting-sort tiles into bucketed pairs ----------------

__global__ __launch_bounds__(256) void k_p1(const int* __restrict__ ei,
                                            unsigned long long* __restrict__ pairs,
                                            int* __restrict__ cursor, int E, int B) {
    __shared__ unsigned long long pl[T1];            // 16 KB
    __shared__ int hist[256], base[256], gbase[256], lcnt[256], scanbuf[256];
    int tid = threadIdx.x;
    int tile0 = blockIdx.x * T1;
    int cnt = min(T1, E - tile0);

    hist[tid] = 0; lcnt[tid] = 0;
    __syncthreads();

    int s[T1 / 256], d[T1 / 256];
#pragma unroll
    for (int i = 0; i < T1 / 256; ++i) {
        int k = i * 256 + tid;
        if (k < cnt) {
            s[i] = ei[tile0 + k];
            d[i] = ei[E + tile0 + k];
            atomicAdd(&hist[d[i] >> GSH], 1);
        }
    }
    __syncthreads();

    int h = hist[tid];
    scanbuf[tid] = h;
    __syncthreads();
    for (int off = 1; off < 256; off <<= 1) {
        int t = (tid >= (unsigned)off) ? scanbuf[tid - off] : 0;
        __syncthreads();
        scanbuf[tid] += t;
        __syncthreads();
    }
    base[tid] = scanbuf[tid] - h;
    gbase[tid] = (tid < B && h > 0) ? atomicAdd(&cursor[tid], h) : 0;
    __syncthreads();

#pragma unroll
    for (int i = 0; i < T1 / 256; ++i) {
        int k = i * 256 + tid;
        if (k < cnt) {
            int b = d[i] >> GSH;
            int pos = base[b] + atomicAdd(&lcnt[b], 1);
            pl[pos] = ((unsigned long long)(unsigned)d[i] << 32) | (unsigned)s[i];
        }
    }
    __syncthreads();

    for (int k = tid; k < cnt; k += 256) {
        unsigned long long p = pl[k];
        int b = (int)(p >> (32 + GSH));
        pairs[(size_t)gbase[b] + (k - base[b])] = p;
    }
}

// ---------------- bucket-count scan -> csrBase; rowptr[N] = E ----------------

__global__ void k_bscan(const int* __restrict__ cursor, int* __restrict__ csrBase,
                        int* __restrict__ rowptr, int B, int E, int N) {
    __shared__ int sh[256];
    int t = threadIdx.x;
    int c = (t < B) ? cursor[t] - t * STRIDE : 0;
    sh[t] = c;
    __syncthreads();
    for (int off = 1; off < 256; off <<= 1) {
        int u = (t >= off) ? sh[t - off] : 0;
        __syncthreads();
        sh[t] += u;
        __syncthreads();
    }
    if (t < B) csrBase[t] = sh[t] - c;
    if (t == 0) rowptr[N] = E;
}

// ---------------- phase 2: per-bucket CSR scatter + deg/dinv/rowptr ----------------

__global__ __launch_bounds__(512) void k_p2(const unsigned long long* __restrict__ pairs,
                                            const int* __restrict__ cursor,
                                            const int* __restrict__ csrBase,
                                            int* __restrict__ csr, int* __restrict__ rowptr,
                                            float* __restrict__ dinv, int N) {
    __shared__ int hist[GRP], cur[GRP], scanbuf[GRP];
    int t = threadIdx.x;
    int b = blockIdx.x;
    int v0 = b << GSH;
    size_t reg0 = (size_t)b * STRIDE;
    int cnt = cursor[b] - b * STRIDE;

    hist[t] = 0;
    __syncthreads();
    for (int k = t; k < cnt; k += GRP)
        atomicAdd(&hist[(int)(pairs[reg0 + k] >> 32) - v0], 1);
    __syncthreads();

    int h = hist[t];
    scanbuf[t] = h;
    __syncthreads();
    for (int off = 1; off < GRP; off <<= 1) {
        int u = (t >= off) ? scanbuf[t - off] : 0;
        __syncthreads();
        scanbuf[t] += u;
        __syncthreads();
    }
    int excl = scanbuf[t] - h;
    int cB = csrBase[b];
    int v = v0 + t;
    if (v < N) {
        rowptr[v] = cB + excl;
        dinv[v] = rsqrtf((float)(h + 1));
    }
    cur[t] = excl;
    __syncthreads();

    for (int k = t; k < cnt; k += GRP) {
        unsigned long long p = pairs[reg0 + k];
        int l = (int)(p >> 32) - v0;
        int pos = atomicAdd(&cur[l], 1);
        csr[cB + pos] = (int)(p & 0xffffffffu);
    }
}

// ---------------- GEMM1 (MFMA, fused fp32->bf16 + dinv scale on A) ----------------

__global__ __launch_bounds__(256) void k_gemm1(const float* __restrict__ x,
                                               const float* __restrict__ W1,
                                               const float* __restrict__ dinv,
                                               unsigned short* __restrict__ A1, int N) {
    __shared__ unsigned short Wt[EMBED * 136];       // W^T, K padded 128->136
    for (int i = threadIdx.x; i < FEAT * EMBED; i += 256) {
        int k = i >> 6, n = i & 63;
        Wt[n * 136 + k] = f2bf(W1[i]);
    }
    __syncthreads();

    int wv = threadIdx.x >> 6, lane = threadIdx.x & 63;
    int g = lane >> 4, r = lane & 15;
    int arow = blockIdx.x * 64 + wv * 16 + r;
    bool rowok = arow < N;
    float dv = rowok ? dinv[arow] : 0.f;

    s8v a[4];
#pragma unroll
    for (int ks = 0; ks < 4; ++ks) {
        if (rowok) {
            const float* p = x + (size_t)arow * FEAT + ks * 32 + g * 8;
            float4 p0 = *(const float4*)p;
            float4 p1 = *(const float4*)(p + 4);
            s8v t;
            t[0] = (short)f2bf(p0.x * dv); t[1] = (short)f2bf(p0.y * dv);
            t[2] = (short)f2bf(p0.z * dv); t[3] = (short)f2bf(p0.w * dv);
            t[4] = (short)f2bf(p1.x * dv); t[5] = (short)f2bf(p1.y * dv);
            t[6] = (short)f2bf(p1.z * dv); t[7] = (short)f2bf(p1.w * dv);
            a[ks] = t;
        } else {
            s8v z = {};
            a[ks] = z;
        }
    }

    f32x4 acc[4];
#pragma unroll
    for (int nt = 0; nt < 4; ++nt) acc[nt] = (f32x4){0.f, 0.f, 0.f, 0.f};

#pragma unroll
    for (int nt = 0; nt < 4; ++nt) {
        int n0 = nt * 16;
#pragma unroll
        for (int ks = 0; ks < 4; ++ks) {
            s8v bfr = *(const s8v*)&Wt[(n0 + r) * 136 + ks * 32 + g * 8];
            acc[nt] = __builtin_amdgcn_mfma_f32_16x16x32_bf16(a[ks], bfr, acc[nt], 0, 0, 0);
        }
    }

    int orow0 = blockIdx.x * 64 + wv * 16 + g * 4;
#pragma unroll
    for (int nt = 0; nt < 4; ++nt)
#pragma unroll
        for (int q = 0; q < 4; ++q) {
            int orow = orow0 + q;
            if (orow < N) A1[(size_t)orow * EMBED + nt * 16 + r] = f2bf(acc[nt][q]);
        }
}

// ---------------- pipelined wide gather (2 nodes/wave) ----------------
// rs = lane>>3 (slot 0..7), dp = (lane&7)*8 (8 dims = 16B per lane).
// Virtual index list per node: positions 0..cnt-2 = csr[beg..], cnt-1 = self.
// Main straight-line path covers positions 0..31 (4 strided groups); masked
// slots load the (valid) self row and skip the accumulate. Uniform tail loop
// handles cnt>32. All idx loads for BOTH nodes issue before any row load;
// all row loads issue before any accumulate -> one idx round + one row round.

struct I4 { int s0, s1, s2, s3; };
struct R4 { s8v u0, u1, u2, u3; };

static __device__ __forceinline__ I4 g_idx(const int* __restrict__ csr,
                                           int beg, int cnt, int v, int rs) {
    I4 r;
    r.s0 = (rs      < cnt - 1) ? csr[beg + rs]      : v;
    r.s1 = (rs + 8  < cnt - 1) ? csr[beg + rs + 8]  : v;
    r.s2 = (rs + 16 < cnt - 1) ? csr[beg + rs + 16] : v;
    r.s3 = (rs + 24 < cnt - 1) ? csr[beg + rs + 24] : v;
    return r;
}
static __device__ __forceinline__ R4 g_rows(const unsigned short* __restrict__ T,
                                            const I4& i, int dp) {
    R4 r;
    r.u0 = *(const s8v*)(T + (size_t)i.s0 * EMBED + dp);
    r.u1 = *(const s8v*)(T + (size_t)i.s1 * EMBED + dp);
    r.u2 = *(const s8v*)(T + (size_t)i.s2 * EMBED + dp);
    r.u3 = *(const s8v*)(T + (size_t)i.s3 * EMBED + dp);
    return r;
}
static __device__ __forceinline__ void accu(float* a, s8v u) {
#pragma unroll
    for (int i = 0; i < 8; ++i) a[i] += bf2f((unsigned short)u[i]);
}
static __device__ __forceinline__ void g_acc(const R4& r, int rs, int cnt, float* a) {
    if (rs < cnt)      accu(a, r.u0);
    if (rs + 8 < cnt)  accu(a, r.u1);
    if (rs + 16 < cnt) accu(a, r.u2);
    if (rs + 24 < cnt) accu(a, r.u3);
}
static __device__ __forceinline__ void g_tail(const unsigned short* __restrict__ T,
                                              const int* __restrict__ csr,
                                              int beg, int cnt, int v, int rs, int dp,
                                              float* a) {
    for (int p = 32 + rs; p < cnt; p += 8) {
        int s = (p < cnt - 1) ? csr[beg + p] : v;
        s8v u = *(const s8v*)(T + (size_t)s * EMBED + dp);
        accu(a, u);
    }
}
static __device__ __forceinline__ void fold8(float* a) {
#pragma unroll
    for (int o = 8; o < 64; o <<= 1) {
#pragma unroll
        for (int i = 0; i < 8; ++i) a[i] += __shfl_xor(a[i], o);
    }
}

// gather layer 1: Hb = bf16( dinv * relu(dinv*sum + b1) )   (sum includes self)
__global__ __launch_bounds__(256) void k_gf1(const int* __restrict__ rowptr,
                                             const int* __restrict__ csr,
                                             const unsigned short* __restrict__ A1,
                                             const float* __restrict__ dinv,
                                             const float* __restrict__ b1,
                                             unsigned short* __restrict__ Hb, int N) {
    int wv = threadIdx.x >> 6, lane = threadIdx.x & 63;
    int va = (blockIdx.x * 4 + wv) * 2;
    if (va >= N) return;
    int vb = va + 1;
    bool okB = vb < N;
    int vB = okB ? vb : va;
    int rs = lane >> 3, dp = (lane & 7) * 8;

    int2 rp01 = *(const int2*)(rowptr + va);         // va even -> 8B aligned
    int rp2 = okB ? rowptr[vb + 1] : rp01.y;
    float dvA = dinv[va];
    float dvB = okB ? dinv[vb] : 0.f;
    float4 bL = *(const float4*)(b1 + dp);
    float4 bH = *(const float4*)(b1 + dp + 4);

    int begA = rp01.x, cntA = rp01.y - rp01.x + 1;
    int begB = rp01.y, cntB = okB ? (rp2 - rp01.y + 1) : 0;

    I4 iA = g_idx(csr, begA, cntA, va, rs);
    I4 iB = g_idx(csr, begB, cntB, vB, rs);
    R4 rA = g_rows(A1, iA, dp);
    R4 rB = g_rows(A1, iB, dp);

    float aA[8] = {0,0,0,0,0,0,0,0}, aB[8] = {0,0,0,0,0,0,0,0};
    g_acc(rA, rs, cntA, aA);
    g_acc(rB, rs, cntB, aB);
    if (cntA > 32) g_tail(A1, csr, begA, cntA, va, rs, dp, aA);
    if (cntB > 32) g_tail(A1, csr, begB, cntB, vB, rs, dp, aB);

    fold8(aA);
    fold8(aB);

    if (rs == 0) {
        s8v o;
        float h;
        h = fmaxf(dvA * aA[0] + bL.x, 0.f); o[0] = (short)f2bf(h * dvA);
        h = fmaxf(dvA * aA[1] + bL.y, 0.f); o[1] = (short)f2bf(h * dvA);
        h = fmaxf(dvA * aA[2] + bL.z, 0.f); o[2] = (short)f2bf(h * dvA);
        h = fmaxf(dvA * aA[3] + bL.w, 0.f); o[3] = (short)f2bf(h * dvA);
        h = fmaxf(dvA * aA[4] + bH.x, 0.f); o[4] = (short)f2bf(h * dvA);
        h = fmaxf(dvA * aA[5] + bH.y, 0.f); o[5] = (short)f2bf(h * dvA);
        h = fmaxf(dvA * aA[6] + bH.z, 0.f); o[6] = (short)f2bf(h * dvA);
        h = fmaxf(dvA * aA[7] + bH.w, 0.f); o[7] = (short)f2bf(h * dvA);
        *(s8v*)(Hb + (size_t)va * EMBED + dp) = o;
        if (okB) {
            s8v p;
            h = fmaxf(dvB * aB[0] + bL.x, 0.f); p[0] = (short)f2bf(h * dvB);
            h = fmaxf(dvB * aB[1] + bL.y, 0.f); p[1] = (short)f2bf(h * dvB);
            h = fmaxf(dvB * aB[2] + bL.z, 0.f); p[2] = (short)f2bf(h * dvB);
            h = fmaxf(dvB * aB[3] + bL.w, 0.f); p[3] = (short)f2bf(h * dvB);
            h = fmaxf(dvB * aB[4] + bH.x, 0.f); p[4] = (short)f2bf(h * dvB);
            h = fmaxf(dvB * aB[5] + bH.y, 0.f); p[5] = (short)f2bf(h * dvB);
            h = fmaxf(dvB * aB[6] + bH.z, 0.f); p[6] = (short)f2bf(h * dvB);
            h = fmaxf(dvB * aB[7] + bH.w, 0.f); p[7] = (short)f2bf(h * dvB);
            *(s8v*)(Hb + (size_t)vb * EMBED + dp) = p;
        }
    }
}

// gather layer 2 (linearity): Pb = bf16( dinv[v] * sum Hb )   (sum includes self)
__global__ __launch_bounds__(256) void k_gf2h(const int* __restrict__ rowptr,
                                              const int* __restrict__ csr,
                                              const unsigned short* __restrict__ Hb,
                                              const float* __restrict__ dinv,
                                              unsigned short* __restrict__ Pb, int N) {
    int wv = threadIdx.x >> 6, lane = threadIdx.x & 63;
    int va = (blockIdx.x * 4 + wv) * 2;
    if (va >= N) return;
    int vb = va + 1;
    bool okB = vb < N;
    int vB = okB ? vb : va;
    int rs = lane >> 3, dp = (lane & 7) * 8;

    int2 rp01 = *(const int2*)(rowptr + va);
    int rp2 = okB ? rowptr[vb + 1] : rp01.y;
    float dvA = dinv[va];
    float dvB = okB ? dinv[vb] : 0.f;

    int begA = rp01.x, cntA = rp01.y - rp01.x + 1;
    int begB = rp01.y, cntB = okB ? (rp2 - rp01.y + 1) : 0;

    I4 iA = g_idx(csr, begA, cntA, va, rs);
    I4 iB = g_idx(csr, begB, cntB, vB, rs);
    R4 rA = g_rows(Hb, iA, dp);
    R4 rB = g_rows(Hb, iB, dp);

    float aA[8] = {0,0,0,0,0,0,0,0}, aB[8] = {0,0,0,0,0,0,0,0};
    g_acc(rA, rs, cntA, aA);
    g_acc(rB, rs, cntB, aB);
    if (cntA > 32) g_tail(Hb, csr, begA, cntA, va, rs, dp, aA);
    if (cntB > 32) g_tail(Hb, csr, begB, cntB, vB, rs, dp, aB);

    fold8(aA);
    fold8(aB);

    if (rs == 0) {
        s8v o;
#pragma unroll
        for (int i = 0; i < 8; ++i) o[i] = (short)f2bf(dvA * aA[i]);
        *(s8v*)(Pb + (size_t)va * EMBED + dp) = o;
        if (okB) {
            s8v p;
#pragma unroll
            for (int i = 0; i < 8; ++i) p[i] = (short)f2bf(dvB * aB[i]);
            *(s8v*)(Pb + (size_t)vb * EMBED + dp) = p;
        }
    }
}

// ---------------- final: out = log_softmax(Pb @ W2 + b2) (MFMA + fused softmax) ----------------

__global__ __launch_bounds__(256) void k_fin(const unsigned short* __restrict__ Pb,
                                             const float* __restrict__ W2,
                                             const float* __restrict__ b2,
                                             float* __restrict__ out, int N) {
    __shared__ unsigned short Wt[48 * 72];           // W2^T, cols padded 40->48, K 64->72
    for (int i = threadIdx.x; i < 48 * EMBED; i += 256) {
        int n = i >> 6, k = i & 63;
        Wt[n * 72 + k] = (n < CLS) ? f2bf(W2[k * CLS + n]) : 0;
    }
    __syncthreads();

    int wv = threadIdx.x >> 6, lane = threadIdx.x & 63;
    int g = lane >> 4, r = lane & 15;
    int arow = blockIdx.x * 64 + wv * 16 + r;

    s8v z = {};
    s8v a[2];
#pragma unroll
    for (int ks = 0; ks < 2; ++ks)
        a[ks] = (arow < N) ? *(const s8v*)(Pb + (size_t)arow * EMBED + ks * 32 + g * 8) : z;

    f32x4 acc[3];
#pragma unroll
    for (int nt = 0; nt < 3; ++nt) acc[nt] = (f32x4){0.f, 0.f, 0.f, 0.f};

#pragma unroll
    for (int nt = 0; nt < 3; ++nt)
#pragma unroll
        for (int ks = 0; ks < 2; ++ks) {
            s8v bfr = *(const s8v*)&Wt[(nt * 16 + r) * 72 + ks * 32 + g * 8];
            acc[nt] = __builtin_amdgcn_mfma_f32_16x16x32_bf16(a[ks], bfr, acc[nt], 0, 0, 0);
        }

    int orow0 = blockIdx.x * 64 + wv * 16 + g * 4;
    bool v2 = r < (CLS - 32);
#pragma unroll
    for (int q = 0; q < 4; ++q) {
        float l0 = acc[0][q] + b2[r];
        float l1 = acc[1][q] + b2[16 + r];
        float l2 = v2 ? acc[2][q] + b2[32 + r] : -INFINITY;
        float m = fmaxf(fmaxf(l0, l1), l2);
#pragma unroll
        for (int o = 1; o < 16; o <<= 1) m = fmaxf(m, __shfl_xor(m, o));
        float se = __expf(l0 - m) + __expf(l1 - m) + (v2 ? __expf(l2 - m) : 0.f);
#pragma unroll
        for (int o = 1; o < 16; o <<= 1) se += __shfl_xor(se, o);
        float lse = m + __logf(se);
        int orow = orow0 + q;
        if (orow < N) {
            float* op = out + (size_t)orow * CLS;
            op[r] = l0 - lse;
            op[16 + r] = l1 - lse;
            if (v2) op[32 + r] = l2 - lse;
        }
    }
}

// ---------------- launch ----------------

extern "C" void kernel_launch(void* const* d_in, const int* in_sizes, int n_in,
                              void* d_out, int out_size, void* d_ws, size_t ws_size,
                              hipStream_t stream) {
    const float* x  = (const float*)d_in[0];
    const int*   ei = (const int*)d_in[1];
    const float* W1 = (const float*)d_in[2];
    const float* b1 = (const float*)d_in[3];
    const float* W2 = (const float*)d_in[4];
    const float* b2 = (const float*)d_in[5];
    float* out = (float*)d_out;

    const int N = in_sizes[0] / FEAT;           // 100000
    const int E = in_sizes[1] / 2;              // 1600000
    const int B = (N + GRP - 1) >> GSH;         // 196 buckets (<=256)

    char* ws = (char*)d_ws;
    size_t off = 0;
    auto alloc = [&](size_t bytes) { char* p = ws + off; off = (off + bytes + 255) & ~(size_t)255; return p; };
    int*   cursor  = (int*)alloc(256 * 4);
    int*   csrBase = (int*)alloc(256 * 4);
    float* dinv    = (float*)alloc((size_t)N * 4);
    int*   rowptr  = (int*)alloc((size_t)(N + 1) * 4);
    int*   csr     = (int*)alloc((size_t)E * 4);
    // union region: pairs (19.3 MB) dead before A1/Hb written; Pb aliases A1 (dead after gf1)
    size_t regA = (size_t)B * STRIDE * 8;
    size_t regB = (size_t)N * EMBED * 4;        // A1 + Hb
    char*  region = alloc(regA > regB ? regA : regB);
    unsigned long long* pairs = (unsigned long long*)region;
    unsigned short* A1 = (unsigned short*)region;
    unsigned short* Hb = (unsigned short*)(region + (size_t)N * EMBED * 2);
    unsigned short* Pb = A1;                    // gf2h reads Hb, writes Pb (disjoint halves)

    k_initcur<<<1, 256, 0, stream>>>(cursor, B);
    k_p1<<<(E + T1 - 1) / T1, 256, 0, stream>>>(ei, pairs, cursor, E, B);
    k_bscan<<<1, 256, 0, stream>>>(cursor, csrBase, rowptr, B, E, N);
    k_p2<<<B, GRP, 0, stream>>>(pairs, cursor, csrBase, csr, rowptr, dinv, N);

    k_gemm1<<<(N + 63) / 64, 256, 0, stream>>>(x, W1, dinv, A1, N);
    k_gf1<<<(N + 7) / 8, 256, 0, stream>>>(rowptr, csr, A1, dinv, b1, Hb, N);
    k_gf2h<<<(N + 7) / 8, 256, 0, stream>>>(rowptr, csr, Hb, dinv, Pb, N);
    k_fin<<<(N + 63) / 64, 256, 0, stream>>>(Pb, W2, b2, out, N);
}